// Round 3
// baseline (1352.867 us; speedup 1.0000x reference)
//
#include <hip/hip_runtime.h>
#include <math.h>

// ---------------------------------------------------------------------------
// GraphSAGE-attention forward, fp32 (round 3: randint uses XOR of both
// threefry output words -- partitionable random_bits folds 64->32 via XOR).
//
// RNG chain (jax_threefry_partitionable=True, default on modern JAX):
//   K  = threefry2x32((0,42), (0, mp*16+li))        # fold_in
//   k2 = threefry2x32(K, (0,1))                     # split(key,2)[1] (foldlike)
//   (b0,b1) = threefry2x32(k2, (0,i))
//   col_i = (b0 ^ b1) & 31                          # random_bits32 = b0^b1; %32
// Legacy fallback (RNG_LEGACY=1): original (non-partitionable) mode.
// ---------------------------------------------------------------------------

#define RNG_LEGACY 0

__host__ __device__ __forceinline__ void tf2x32(unsigned k0, unsigned k1,
                                                unsigned x0, unsigned x1,
                                                unsigned& o0, unsigned& o1) {
  const unsigned ks2 = k0 ^ k1 ^ 0x1BD11BDAu;
  unsigned v0 = x0 + k0, v1 = x1 + k1;
#define TFR(r) { v0 += v1; v1 = (v1 << (r)) | (v1 >> (32 - (r))); v1 ^= v0; }
  TFR(13) TFR(15) TFR(26) TFR(6)
  v0 += k1;  v1 += ks2 + 1u;
  TFR(17) TFR(29) TFR(16) TFR(24)
  v0 += ks2; v1 += k0 + 2u;
  TFR(13) TFR(15) TFR(26) TFR(6)
  v0 += k0;  v1 += k1 + 3u;
  TFR(17) TFR(29) TFR(16) TFR(24)
  v0 += k1;  v1 += ks2 + 4u;
  TFR(13) TFR(15) TFR(26) TFR(6)
  v0 += ks2; v1 += k0 + 5u;
#undef TFR
  o0 = v0; o1 = v1;
}

// frontier: dst[i] = adj[src[i>>4]*32 + col_i], i in [0, n)
__global__ void frontier_kernel(const int* __restrict__ adj,
                                const int* __restrict__ src,
                                int* __restrict__ dst,
                                int n, unsigned k0, unsigned k1) {
  int idx = blockIdx.x * blockDim.x + threadIdx.x;
  if (idx >= n) return;
  unsigned y0, y1, bits;
#if RNG_LEGACY
  int half = n >> 1;
  if (idx < half) { tf2x32(k0, k1, (unsigned)idx, (unsigned)(half + idx), y0, y1); bits = y0; }
  else            { tf2x32(k0, k1, (unsigned)(idx - half), (unsigned)idx, y0, y1); bits = y1; }
#else
  tf2x32(k0, k1, 0u, (unsigned)idx, y0, y1);
  bits = y0 ^ y1;
#endif
  int col = (int)(bits & 31u);
  int parent = src[idx >> 4];
  dst[idx] = adj[(size_t)parent * 32 + col];
}

// ---------------------------------------------------------------------------
// Generic 128x128-tile fp32 GEMM: C[r, hb*128+c] = sum_j A[row(r), j]*W[...]
// A rows optionally gathered. W row stride fixed 128 (W_prep and Wa1).
// ---------------------------------------------------------------------------
__global__ __launch_bounds__(256) void gemm_k(
    const float* __restrict__ A, const int* __restrict__ gather,
    const float* __restrict__ W, float* __restrict__ C,
    int D, int ldc, size_t w_head_stride) {
  const int t = threadIdx.x;
  const int tx = t & 15, ty = t >> 4;
  const int hb = blockIdx.y;
  const int r0 = blockIdx.x * 128;

  __shared__ float As[16][128];   // [k][row]
  __shared__ float Bs[16][128];   // [k][col]
  float acc[8][8] = {};

  const float* Wb = W + (size_t)hb * w_head_stride;
  const int r = t >> 1, ko = (t & 1) * 8;
  const int arowi = gather ? gather[r0 + r] : (r0 + r);
  const float* arow = A + (size_t)arowi * D + ko;
  const int cb = (t & 31) * 4, jb = t >> 5;

  for (int j0 = 0; j0 < D; j0 += 16) {
    float4 v0 = *(const float4*)(arow + j0);
    float4 v1 = *(const float4*)(arow + j0 + 4);
    As[ko + 0][r] = v0.x; As[ko + 1][r] = v0.y; As[ko + 2][r] = v0.z; As[ko + 3][r] = v0.w;
    As[ko + 4][r] = v1.x; As[ko + 5][r] = v1.y; As[ko + 6][r] = v1.z; As[ko + 7][r] = v1.w;
    const float* wrow = Wb + (size_t)(j0 + jb) * 128 + cb;
    *(float4*)&Bs[jb][cb]     = *(const float4*)wrow;
    *(float4*)&Bs[jb + 8][cb] = *(const float4*)(wrow + 8 * 128);
    __syncthreads();
#pragma unroll
    for (int kk = 0; kk < 16; ++kk) {
      float a[8], b[8];
      *(float4*)&a[0] = *(const float4*)&As[kk][ty * 8];
      *(float4*)&a[4] = *(const float4*)&As[kk][ty * 8 + 4];
      *(float4*)&b[0] = *(const float4*)&Bs[kk][tx * 8];
      *(float4*)&b[4] = *(const float4*)&Bs[kk][tx * 8 + 4];
#pragma unroll
      for (int q = 0; q < 8; ++q)
#pragma unroll
        for (int p = 0; p < 8; ++p)
          acc[q][p] = fmaf(a[q], b[p], acc[q][p]);
    }
    __syncthreads();
  }
  const int c0 = hb * 128;
#pragma unroll
  for (int q = 0; q < 8; ++q) {
    float* cp = C + (size_t)(r0 + ty * 8 + q) * ldc + c0 + tx * 8;
    *(float4*)cp = *(float4*)&acc[q][0];
    *(float4*)(cp + 4) = *(float4*)&acc[q][4];
  }
}

// ---------------------------------------------------------------------------
// AGGSC: per block = 8 m-rows (128 (i,s) rows) x 1 head.
// U = nb @ Wa1_bot, score = sum_c tanh(U + T)*wa2, softmax_s -> alpha.
// ---------------------------------------------------------------------------
__global__ __launch_bounds__(256) void aggsc_kernel(
    const float* __restrict__ NB,   // [m*16, D]
    const float* __restrict__ T,    // [m, 512]
    const float* __restrict__ Wa1,  // [4, 2D, 128]
    const float* __restrict__ wa2,  // [4, 128]
    float* __restrict__ alpha,      // [m, 4, 16]
    int D) {
  const int t = threadIdx.x;
  const int tx = t & 15, ty = t >> 4;
  const int hb = blockIdx.y;
  const int i0 = blockIdx.x * 8;
  const int rowbase = i0 * 16;

  __shared__ float As[16][128];
  __shared__ float Bs[16][128];
  __shared__ float Ts[8][128];
  __shared__ float w2s[128];
  __shared__ float ps[128][17];
  __shared__ float sc[128];

  float acc[8][8] = {};
  const float* Wb = Wa1 + ((size_t)hb * 2 * D + D) * 128;  // bottom half
  const int r = t >> 1, ko = (t & 1) * 8;
  const float* arow = NB + (size_t)(rowbase + r) * D + ko;
  const int cb = (t & 31) * 4, jb = t >> 5;

  for (int j0 = 0; j0 < D; j0 += 16) {
    float4 v0 = *(const float4*)(arow + j0);
    float4 v1 = *(const float4*)(arow + j0 + 4);
    As[ko + 0][r] = v0.x; As[ko + 1][r] = v0.y; As[ko + 2][r] = v0.z; As[ko + 3][r] = v0.w;
    As[ko + 4][r] = v1.x; As[ko + 5][r] = v1.y; As[ko + 6][r] = v1.z; As[ko + 7][r] = v1.w;
    const float* wrow = Wb + (size_t)(j0 + jb) * 128 + cb;
    *(float4*)&Bs[jb][cb]     = *(const float4*)wrow;
    *(float4*)&Bs[jb + 8][cb] = *(const float4*)(wrow + 8 * 128);
    __syncthreads();
#pragma unroll
    for (int kk = 0; kk < 16; ++kk) {
      float a[8], b[8];
      *(float4*)&a[0] = *(const float4*)&As[kk][ty * 8];
      *(float4*)&a[4] = *(const float4*)&As[kk][ty * 8 + 4];
      *(float4*)&b[0] = *(const float4*)&Bs[kk][tx * 8];
      *(float4*)&b[4] = *(const float4*)&Bs[kk][tx * 8 + 4];
#pragma unroll
      for (int q = 0; q < 8; ++q)
#pragma unroll
        for (int p = 0; p < 8; ++p)
          acc[q][p] = fmaf(a[q], b[p], acc[q][p]);
    }
    __syncthreads();
  }

  {  // stage T tile [8 i][128 c] and wa2
    int flat = t * 4;
    int il = flat >> 7, c = flat & 127;
    *(float4*)&Ts[il][c] = *(const float4*)(T + (size_t)(i0 + il) * 512 + hb * 128 + c);
    if (t < 32) *(float4*)&w2s[t * 4] = *(const float4*)(wa2 + hb * 128 + t * 4);
  }
  __syncthreads();

  const int il = ty >> 1;
#pragma unroll
  for (int q = 0; q < 8; ++q) {
    float s = 0.f;
#pragma unroll
    for (int p = 0; p < 8; ++p) {
      int c = tx * 8 + p;
      float e = tanhf(acc[q][p] + Ts[il][c]);
      s = fmaf(e, w2s[c], s);
    }
    ps[ty * 8 + q][tx] = s;
  }
  __syncthreads();
  if (t < 128) {
    float s = 0.f;
#pragma unroll
    for (int x = 0; x < 16; ++x) s += ps[t][x];
    sc[t] = s;
  }
  __syncthreads();
  if (t < 8) {
    float mx = -3.4e38f;
#pragma unroll
    for (int s_ = 0; s_ < 16; ++s_) mx = fmaxf(mx, sc[t * 16 + s_]);
    float ex[16], sum = 0.f;
#pragma unroll
    for (int s_ = 0; s_ < 16; ++s_) { ex[s_] = expf(sc[t * 16 + s_] - mx); sum += ex[s_]; }
    float inv = 1.f / sum;
    float* ap = alpha + ((size_t)(i0 + t) * 4 + hb) * 16;
#pragma unroll
    for (int s_ = 0; s_ < 16; ++s_) ap[s_] = ex[s_] * inv;
  }
}

// ---------------------------------------------------------------------------
// OUT: per block 16 m-rows. aggv = sum_s alpha*nb, out = relu(x@Wx + aggv@Wn).
// ---------------------------------------------------------------------------
template <int D>
__global__ __launch_bounds__(256) void out_kernel(
    const float* __restrict__ X,      // [m, D]
    const float* __restrict__ NB,     // [m*16, D]
    const float* __restrict__ alpha,  // [m, 4, 16]
    const float* __restrict__ Wx,     // [4, D, 64]
    const float* __restrict__ Wn,     // [4, D, 64]
    float* __restrict__ out) {        // [m, 256]
  constexpr int DP = D + 4;
  const int t = threadIdx.x;
  const int i0 = blockIdx.x * 16;
  __shared__ float al[16 * 4 * 16];
  __shared__ float agg[16 * 4 * DP];
  __shared__ float xs[16 * DP];

  ((float4*)al)[t] = ((const float4*)(alpha + (size_t)i0 * 64))[t];
  {
    constexpr int CH = (16 * D) / (256 * 4);
#pragma unroll
    for (int q = 0; q < CH; ++q) {
      int flat = t + q * 256;
      int i = flat / (D / 4);
      int cj = flat % (D / 4);
      *(float4*)&xs[i * DP + cj * 4] = *(const float4*)(X + (size_t)(i0 + i) * D + cj * 4);
    }
  }
  __syncthreads();

  {  // agg phase
    constexpr int IPC = 256 / D;
    int ip, h, jg;
    if (IPC == 2) { ip = t >> 7; h = (t >> 5) & 3; jg = t & 31; }
    else          { ip = 0;      h = t >> 6;       jg = t & 63; }
    for (int ii = 0; ii < 16; ii += IPC) {
      int i = ii + ip;
      float4 a = {0.f, 0.f, 0.f, 0.f};
      const float* nbp = NB + (size_t)(i0 + i) * 16 * D + jg * 4;
#pragma unroll
      for (int s = 0; s < 16; ++s) {
        float4 v = *(const float4*)(nbp + (size_t)s * D);
        float w = al[(i * 4 + h) * 16 + s];
        a.x = fmaf(w, v.x, a.x); a.y = fmaf(w, v.y, a.y);
        a.z = fmaf(w, v.z, a.z); a.w = fmaf(w, v.w, a.w);
      }
      *(float4*)&agg[(i * 4 + h) * DP + jg * 4] = a;
    }
  }
  __syncthreads();

  {  // out phase
    const int i = t >> 4, o = (t & 15) * 4;
    float acc[4][4];
#pragma unroll
    for (int h = 0; h < 4; ++h)
#pragma unroll
      for (int w = 0; w < 4; ++w) acc[h][w] = 0.f;
#pragma unroll 2
    for (int j = 0; j < D; ++j) {
      float xv = xs[i * DP + j];
#pragma unroll
      for (int h = 0; h < 4; ++h) {
        float av = agg[(i * 4 + h) * DP + j];
        float4 wx = *(const float4*)(Wx + ((size_t)h * D + j) * 64 + o);
        float4 wn = *(const float4*)(Wn + ((size_t)h * D + j) * 64 + o);
        acc[h][0] = fmaf(xv, wx.x, fmaf(av, wn.x, acc[h][0]));
        acc[h][1] = fmaf(xv, wx.y, fmaf(av, wn.y, acc[h][1]));
        acc[h][2] = fmaf(xv, wx.z, fmaf(av, wn.z, acc[h][2]));
        acc[h][3] = fmaf(xv, wx.w, fmaf(av, wn.w, acc[h][3]));
      }
    }
    float* op = out + (size_t)(i0 + i) * 256;
#pragma unroll
    for (int h = 0; h < 4; ++h) {
      float4 r;
      r.x = fmaxf(acc[h][0], 0.f); r.y = fmaxf(acc[h][1], 0.f);
      r.z = fmaxf(acc[h][2], 0.f); r.w = fmaxf(acc[h][3], 0.f);
      *(float4*)(op + h * 64 + o) = r;
    }
  }
}

// ---------------------------------------------------------------------------
extern "C" void kernel_launch(void* const* d_in, const int* in_sizes, int n_in,
                              void* d_out, int out_size, void* d_ws, size_t ws_size,
                              hipStream_t stream) {
  (void)in_sizes; (void)n_in; (void)out_size; (void)ws_size;
  const int*   ids   = (const int*)d_in[0];
  const float* feats = (const float*)d_in[1];
  const int*   adjs  = (const int*)d_in[2];
  const float* Wp    = (const float*)d_in[3];
  const float* Wa1_0 = (const float*)d_in[4];
  const float* wa2_0 = (const float*)d_in[5];
  const float* Wx_0  = (const float*)d_in[6];
  const float* Wn_0  = (const float*)d_in[7];
  const float* Wa1_1 = (const float*)d_in[8];
  const float* wa2_1 = (const float*)d_in[9];
  const float* Wx_1  = (const float*)d_in[10];
  const float* Wn_1  = (const float*)d_in[11];
  float* out = (float*)d_out;

  char* ws = (char*)d_ws;
  const size_t SZ_NODES = (size_t)139776 * 4;
  const size_t SZ_P     = (size_t)139776 * 128 * 4;
  const size_t SZ_T     = (size_t)8192 * 512 * 4;
  const size_t SZ_AL    = (size_t)8192 * 64 * 4;
  const size_t SZ_NF1   = (size_t)8192 * 256 * 4;
  int*   nodes = (int*)ws;
  float* P     = (float*)(ws + SZ_NODES);
  float* T     = (float*)(ws + SZ_NODES + SZ_P);
  float* AL    = (float*)(ws + SZ_NODES + SZ_P + SZ_T);
  float* NF1   = (float*)(ws + SZ_NODES + SZ_P + SZ_T + SZ_AL);
  float* NF0   = (float*)(ws + SZ_NODES + SZ_P + SZ_T + SZ_AL + SZ_NF1);

  for (int mp = 0; mp < 2; ++mp) {
    const int* adj = adjs + (size_t)mp * 200000 * 32;
    const float* wa1_0 = Wa1_0 + (size_t)mp * 4 * 256 * 128;
    const float* w2_0  = wa2_0 + (size_t)mp * 4 * 128;
    const float* wx_0  = Wx_0  + (size_t)mp * 4 * 128 * 64;
    const float* wn_0  = Wn_0  + (size_t)mp * 4 * 128 * 64;
    const float* wa1_1 = Wa1_1 + (size_t)mp * 4 * 512 * 128;
    const float* w2_1  = wa2_1 + (size_t)mp * 4 * 128;
    const float* wx_1  = Wx_1  + (size_t)mp * 4 * 256 * 64;
    const float* wn_1  = Wn_1  + (size_t)mp * 4 * 256 * 64;

    // RNG keys: K = fold_in(key(42), mp*16+li); k2 = split(K,2)[1]
    unsigned key0[2], key1[2];
    for (int li = 0; li < 2; ++li) {
      unsigned K0, K1, s0, s1;
      tf2x32(0u, 42u, 0u, (unsigned)(mp * 16 + li), K0, K1);
#if RNG_LEGACY
      unsigned a0, b0, a1, b1;
      tf2x32(K0, K1, 0u, 2u, a0, b0);
      tf2x32(K0, K1, 1u, 3u, a1, b1);
      s0 = b0; s1 = b1;           // original split child1 = (out1(0,2), out1(1,3))
#else
      tf2x32(K0, K1, 0u, 1u, s0, s1);  // foldlike split child 1
#endif
      key0[li] = s0; key1[li] = s1;
    }

    hipMemcpyAsync(nodes, ids, 512 * sizeof(int), hipMemcpyDeviceToDevice, stream);
    frontier_kernel<<<8192 / 256, 256, 0, stream>>>(adj, ids, nodes + 512, 8192,
                                                    key0[0], key1[0]);
    frontier_kernel<<<131072 / 256, 256, 0, stream>>>(adj, nodes + 512, nodes + 8704,
                                                      131072, key0[1], key1[1]);
    gemm_k<<<dim3(139776 / 128, 1), 256, 0, stream>>>(feats, nodes, Wp, P, 128, 128, 0);

    const float* P0 = P;
    const float* P1 = P + (size_t)512 * 128;
    const float* P2 = P + (size_t)8704 * 128;

    // ---- L0 agg B: x=P1, nb=P2 -> NF1 [8192,256]
    gemm_k<<<dim3(8192 / 128, 4), 256, 0, stream>>>(P1, nullptr, wa1_0, T, 128, 512,
                                                    (size_t)2 * 128 * 128);
    aggsc_kernel<<<dim3(8192 / 8, 4), 256, 0, stream>>>(P2, T, wa1_0, w2_0, AL, 128);
    out_kernel<128><<<8192 / 16, 256, 0, stream>>>(P1, P2, AL, wx_0, wn_0, NF1);

    // ---- L0 agg A: x=P0, nb=P1 -> NF0 [512,256]
    gemm_k<<<dim3(512 / 128, 4), 256, 0, stream>>>(P0, nullptr, wa1_0, T, 128, 512,
                                                   (size_t)2 * 128 * 128);
    aggsc_kernel<<<dim3(512 / 8, 4), 256, 0, stream>>>(P1, T, wa1_0, w2_0, AL, 128);
    out_kernel<128><<<512 / 16, 256, 0, stream>>>(P0, P1, AL, wx_0, wn_0, NF0);

    // ---- L1: x=NF0, nb=NF1 -> d_out[mp]
    gemm_k<<<dim3(512 / 128, 4), 256, 0, stream>>>(NF0, nullptr, wa1_1, T, 256, 512,
                                                   (size_t)2 * 256 * 128);
    aggsc_kernel<<<dim3(512 / 8, 4), 256, 0, stream>>>(NF1, T, wa1_1, w2_1, AL, 256);
    out_kernel<256><<<512 / 16, 256, 0, stream>>>(NF0, NF1, AL, wx_1, wn_1,
                                                  out + (size_t)mp * 512 * 256);
  }
}

// Round 4
// 866.563 us; speedup vs baseline: 1.5612x; 1.5612x over previous
//
#include <hip/hip_runtime.h>
#include <math.h>

// ---------------------------------------------------------------------------
// GraphSAGE-attention forward (round 4: all GEMMs -> bf16 MFMA 16x16x32).
// RNG verified in R3 (partitionable threefry, bits = o0^o1).
//
// Structure per mp:
//   frontier x2 -> nodes[139776]
//   prep  (MFMA, gather, fp32 feats -> bf16 cvt on load): Pb = feats[nodes]@Wp (bf16 out)
//   per agg stage: T = x@Wa1_top (MFMA, fp32 out)
//                  aggsc: U = nb@Wa1_bot (MFMA) + fused tanh/wa2/softmax -> AL
//                  out_kernel: agg = sum_s alpha*nb; relu(x@Wx + agg@Wn) (fp32 VALU)
// Weights pre-transposed+cast to bf16 [head][col][k] once per call (transcast).
// MFMA GEMMs are LDS-free: A/B frags loaded global->reg directly.
// C/D layout (verified m89): col = lane&15, row = (lane>>4)*4 + reg.
// A/B frag: lane l holds 8 contiguous k at row/col = l&15, k0 = (l>>4)*8.
// ---------------------------------------------------------------------------

typedef __attribute__((ext_vector_type(8))) short bf16x8;
typedef __attribute__((ext_vector_type(4))) float f32x4;

__device__ __forceinline__ float b2f(unsigned short u) {
  union { unsigned u; float f; } c; c.u = ((unsigned)u) << 16; return c.f;
}
__device__ __forceinline__ unsigned short f2b(float f) {
  union { float f; unsigned u; } c; c.f = f;
  return (unsigned short)((c.u + 0x7FFFu + ((c.u >> 16) & 1u)) >> 16);
}

__host__ __device__ __forceinline__ void tf2x32(unsigned k0, unsigned k1,
                                                unsigned x0, unsigned x1,
                                                unsigned& o0, unsigned& o1) {
  const unsigned ks2 = k0 ^ k1 ^ 0x1BD11BDAu;
  unsigned v0 = x0 + k0, v1 = x1 + k1;
#define TFR(r) { v0 += v1; v1 = (v1 << (r)) | (v1 >> (32 - (r))); v1 ^= v0; }
  TFR(13) TFR(15) TFR(26) TFR(6)
  v0 += k1;  v1 += ks2 + 1u;
  TFR(17) TFR(29) TFR(16) TFR(24)
  v0 += ks2; v1 += k0 + 2u;
  TFR(13) TFR(15) TFR(26) TFR(6)
  v0 += k0;  v1 += k1 + 3u;
  TFR(17) TFR(29) TFR(16) TFR(24)
  v0 += k1;  v1 += ks2 + 4u;
  TFR(13) TFR(15) TFR(26) TFR(6)
  v0 += ks2; v1 += k0 + 5u;
#undef TFR
  o0 = v0; o1 = v1;
}

__global__ void frontier_kernel(const int* __restrict__ adj,
                                const int* __restrict__ src,
                                int* __restrict__ dst,
                                int n, unsigned k0, unsigned k1) {
  int idx = blockIdx.x * blockDim.x + threadIdx.x;
  if (idx >= n) return;
  unsigned y0, y1;
  tf2x32(k0, k1, 0u, (unsigned)idx, y0, y1);
  int col = (int)((y0 ^ y1) & 31u);
  int parent = src[idx >> 4];
  dst[idx] = adj[(size_t)parent * 32 + col];
}

// ---------------------------------------------------------------------------
// transcast: build bf16 transposed weights.
//  Wpt  [128 c][128 k]                 <- Wp[k][c]
//  WT0  [mp][half][h][128 c][128 k]    <- Wa1_0[mp][h][half*128+k][c]
//  WT1  [mp][half][h][128 c][256 k]    <- Wa1_1[mp][h][half*256+k][c]
// ---------------------------------------------------------------------------
__global__ void transcast_kernel(const float* __restrict__ Wp,
                                 const float* __restrict__ Wa1_0,
                                 const float* __restrict__ Wa1_1,
                                 unsigned short* __restrict__ Wpt,
                                 unsigned short* __restrict__ WT0,
                                 unsigned short* __restrict__ WT1) {
  int o = blockIdx.x * 256 + threadIdx.x;
  if (o < 16384) {
    int k = o & 127, c = o >> 7;
    Wpt[o] = f2b(Wp[k * 128 + c]);
  } else if (o < 16384 + 262144) {
    int o2 = o - 16384;
    int k = o2 & 127, c = (o2 >> 7) & 127, h = (o2 >> 14) & 3,
        half = (o2 >> 16) & 1, mpi = (o2 >> 17) & 1;
    WT0[o2] = f2b(Wa1_0[(((size_t)(mpi * 4 + h) * 256) + half * 128 + k) * 128 + c]);
  } else {
    int o3 = o - 16384 - 262144;
    int k = o3 & 255, c = (o3 >> 8) & 127, h = (o3 >> 15) & 3,
        half = (o3 >> 17) & 1, mpi = (o3 >> 18) & 1;
    WT1[o3] = f2b(Wa1_1[(((size_t)(mpi * 4 + h) * 512) + half * 256 + k) * 128 + c]);
  }
}

// ---------------------------------------------------------------------------
// MFMA GEMM: block = 128 rows x 128 cols (grid.y = head block), 4 waves,
// wave = 32 rows x 128 cols, LDS-free.
// MODE 0: store bf16 C [M][ldc]           (prep; A fp32 + gather)
// MODE 1: store f32  C [M][ldc] col hb*128 (T = x @ Wa1_top)
// MODE 2: fused score epilogue -> AL       (U = nb @ Wa1_bot)
// ---------------------------------------------------------------------------
template <int MODE, bool A_F32>
__global__ __launch_bounds__(256) void mfma_gemm(
    const void* __restrict__ Av, const int* __restrict__ gather,
    const unsigned short* __restrict__ WT,  // [NH][128][K] bf16 (col-major)
    const float* __restrict__ Tb,           // MODE2: [m][512]
    const float* __restrict__ wa2,          // MODE2: [4][128]
    void* __restrict__ Cv, float* __restrict__ AL,
    int K, int ldc) {
  const int t = threadIdx.x;
  const int w = t >> 6, l = t & 63;
  const int lr = l & 15, lg = l >> 4;
  const int hb = blockIdx.y;
  const int rbase = blockIdx.x * 128 + w * 32;

  const unsigned short* Wb = WT + (size_t)hb * 128 * K;
  f32x4 acc[2][8] = {};

  int arow[2];
#pragma unroll
  for (int mg = 0; mg < 2; ++mg) {
    int row = rbase + mg * 16 + lr;
    arow[mg] = gather ? gather[row] : row;
  }
  const float* Af = (const float*)Av;
  const unsigned short* Ab = (const unsigned short*)Av;
  const int nks = K >> 5;

  for (int ks = 0; ks < nks; ++ks) {
    const int koff = ks * 32 + lg * 8;
    bf16x8 a[2], b[8];
#pragma unroll
    for (int mg = 0; mg < 2; ++mg) {
      if (A_F32) {
        const float* p = Af + (size_t)arow[mg] * K + koff;
        float4 v0 = *(const float4*)p;
        float4 v1 = *(const float4*)(p + 4);
        union { short s[8]; bf16x8 v; } u;
        u.s[0] = (short)f2b(v0.x); u.s[1] = (short)f2b(v0.y);
        u.s[2] = (short)f2b(v0.z); u.s[3] = (short)f2b(v0.w);
        u.s[4] = (short)f2b(v1.x); u.s[5] = (short)f2b(v1.y);
        u.s[6] = (short)f2b(v1.z); u.s[7] = (short)f2b(v1.w);
        a[mg] = u.v;
      } else {
        a[mg] = *(const bf16x8*)(Ab + (size_t)arow[mg] * K + koff);
      }
    }
#pragma unroll
    for (int f = 0; f < 8; ++f)
      b[f] = *(const bf16x8*)(Wb + (size_t)(f * 16 + lr) * K + koff);
#pragma unroll
    for (int mg = 0; mg < 2; ++mg)
#pragma unroll
      for (int f = 0; f < 8; ++f)
        acc[mg][f] = __builtin_amdgcn_mfma_f32_16x16x32_bf16(a[mg], b[f], acc[mg][f], 0, 0, 0);
  }

  if (MODE == 0) {
    unsigned short* Cb = (unsigned short*)Cv;
#pragma unroll
    for (int mg = 0; mg < 2; ++mg)
#pragma unroll
      for (int f = 0; f < 8; ++f)
#pragma unroll
        for (int r = 0; r < 4; ++r)
          Cb[(size_t)(rbase + mg * 16 + lg * 4 + r) * ldc + f * 16 + lr] =
              f2b(acc[mg][f][r]);
  } else if (MODE == 1) {
    float* Cf = (float*)Cv;
#pragma unroll
    for (int mg = 0; mg < 2; ++mg)
#pragma unroll
      for (int f = 0; f < 8; ++f)
#pragma unroll
        for (int r = 0; r < 4; ++r)
          Cf[(size_t)(rbase + mg * 16 + lg * 4 + r) * ldc + hb * 128 + f * 16 + lr] =
              acc[mg][f][r];
  } else {
    // score epilogue: wave covers 32 NB-rows = 2 m-rows (i) x 16 samples
    const int iw = blockIdx.x * 8 + w * 2;
    float w2[8];
#pragma unroll
    for (int f = 0; f < 8; ++f) w2[f] = wa2[hb * 128 + f * 16 + lr];
#pragma unroll
    for (int mg = 0; mg < 2; ++mg) {
      const int i = iw + mg;
      float tv[8];
#pragma unroll
      for (int f = 0; f < 8; ++f)
        tv[f] = Tb[(size_t)i * 512 + hb * 128 + f * 16 + lr];
      float sc[4];
#pragma unroll
      for (int r = 0; r < 4; ++r) {
        float s = 0.f;
#pragma unroll
        for (int f = 0; f < 8; ++f)
          s += tanhf(acc[mg][f][r] + tv[f]) * w2[f];
        s += __shfl_xor(s, 1); s += __shfl_xor(s, 2);
        s += __shfl_xor(s, 4); s += __shfl_xor(s, 8);
        sc[r] = s;  // score for sample s = lg*4 + r (all 16 lanes of group hold it)
      }
      float mx = fmaxf(fmaxf(sc[0], sc[1]), fmaxf(sc[2], sc[3]));
      mx = fmaxf(mx, __shfl_xor(mx, 16));
      mx = fmaxf(mx, __shfl_xor(mx, 32));
      float e0 = expf(sc[0] - mx), e1 = expf(sc[1] - mx);
      float e2 = expf(sc[2] - mx), e3 = expf(sc[3] - mx);
      float sum = e0 + e1 + e2 + e3;
      sum += __shfl_xor(sum, 16); sum += __shfl_xor(sum, 32);
      float inv = 1.f / sum;
      if (lr == 0) {
        float4 o4 = { e0 * inv, e1 * inv, e2 * inv, e3 * inv };
        *(float4*)(AL + (size_t)i * 64 + hb * 16 + lg * 4) = o4;
      }
    }
  }
}

// ---------------------------------------------------------------------------
// OUT (bf16 in): agg = sum_s alpha*nb; out = relu(x@Wx + agg@Wn).
// D=128: 16 m-rows/block; D=256: 8 m-rows/block.
// ---------------------------------------------------------------------------
template <bool OUTB>
__global__ __launch_bounds__(256) void out128_kernel(
    const unsigned short* __restrict__ X, const unsigned short* __restrict__ NB,
    const float* __restrict__ alpha, const float* __restrict__ Wx,
    const float* __restrict__ Wn, void* __restrict__ outv) {
  constexpr int D = 128, DP = D + 4;
  const int t = threadIdx.x;
  const int i0 = blockIdx.x * 16;
  __shared__ float al[16 * 64];
  __shared__ float agg[16 * 4 * DP];
  __shared__ float xs[16 * DP];

  ((float4*)al)[t] = ((const float4*)(alpha + (size_t)i0 * 64))[t];
#pragma unroll
  for (int q = 0; q < 2; ++q) {
    int flat = t + q * 256;            // 512 chunks of 4 elems
    int i = flat >> 5, cj = flat & 31;
    short4 v = *(const short4*)(X + (size_t)(i0 + i) * D + cj * 4);
    xs[i * DP + cj * 4 + 0] = b2f((unsigned short)v.x);
    xs[i * DP + cj * 4 + 1] = b2f((unsigned short)v.y);
    xs[i * DP + cj * 4 + 2] = b2f((unsigned short)v.z);
    xs[i * DP + cj * 4 + 3] = b2f((unsigned short)v.w);
  }
  __syncthreads();

  {  // agg: 2 i's per pass, h = (t>>5)&3, jg = t&31 (4 cols each)
    int ip = t >> 7, h = (t >> 5) & 3, jg = t & 31;
    for (int ii = 0; ii < 16; ii += 2) {
      int i = ii + ip;
      float a0 = 0.f, a1 = 0.f, a2 = 0.f, a3 = 0.f;
      const unsigned short* nbp = NB + (size_t)(i0 + i) * 16 * D + jg * 4;
#pragma unroll
      for (int s = 0; s < 16; ++s) {
        short4 v = *(const short4*)(nbp + (size_t)s * D);
        float wv = al[(i * 4 + h) * 16 + s];
        a0 = fmaf(wv, b2f((unsigned short)v.x), a0);
        a1 = fmaf(wv, b2f((unsigned short)v.y), a1);
        a2 = fmaf(wv, b2f((unsigned short)v.z), a2);
        a3 = fmaf(wv, b2f((unsigned short)v.w), a3);
      }
      float4 av = {a0, a1, a2, a3};
      *(float4*)&agg[(i * 4 + h) * DP + jg * 4] = av;
    }
  }
  __syncthreads();

  {  // out: i = t>>4, o = (t&15)*4
    const int i = t >> 4, o = (t & 15) * 4;
    float acc[4][4];
#pragma unroll
    for (int h = 0; h < 4; ++h)
#pragma unroll
      for (int x = 0; x < 4; ++x) acc[h][x] = 0.f;
#pragma unroll 2
    for (int j = 0; j < D; ++j) {
      float xv = xs[i * DP + j];
#pragma unroll
      for (int h = 0; h < 4; ++h) {
        float av = agg[(i * 4 + h) * DP + j];
        float4 wx = *(const float4*)(Wx + ((size_t)h * D + j) * 64 + o);
        float4 wn = *(const float4*)(Wn + ((size_t)h * D + j) * 64 + o);
        acc[h][0] = fmaf(xv, wx.x, fmaf(av, wn.x, acc[h][0]));
        acc[h][1] = fmaf(xv, wx.y, fmaf(av, wn.y, acc[h][1]));
        acc[h][2] = fmaf(xv, wx.z, fmaf(av, wn.z, acc[h][2]));
        acc[h][3] = fmaf(xv, wx.w, fmaf(av, wn.w, acc[h][3]));
      }
    }
#pragma unroll
    for (int h = 0; h < 4; ++h) {
      float r0 = fmaxf(acc[h][0], 0.f), r1 = fmaxf(acc[h][1], 0.f);
      float r2 = fmaxf(acc[h][2], 0.f), r3 = fmaxf(acc[h][3], 0.f);
      if (OUTB) {
        ushort4 rb = { f2b(r0), f2b(r1), f2b(r2), f2b(r3) };
        *(ushort4*)((unsigned short*)outv + (size_t)(i0 + i) * 256 + h * 64 + o) = rb;
      } else {
        float4 rf = {r0, r1, r2, r3};
        *(float4*)((float*)outv + (size_t)(i0 + i) * 256 + h * 64 + o) = rf;
      }
    }
  }
}

template <bool OUTB>
__global__ __launch_bounds__(256) void out256_kernel(
    const unsigned short* __restrict__ X, const unsigned short* __restrict__ NB,
    const float* __restrict__ alpha, const float* __restrict__ Wx,
    const float* __restrict__ Wn, void* __restrict__ outv) {
  constexpr int D = 256, DP = D + 4;
  const int t = threadIdx.x;
  const int i0 = blockIdx.x * 8;
  __shared__ float al[8 * 64];
  __shared__ float agg[8 * 4 * DP];
  __shared__ float xs[8 * DP];

  if (t < 128) ((float4*)al)[t] = ((const float4*)(alpha + (size_t)i0 * 64))[t];
#pragma unroll
  for (int q = 0; q < 2; ++q) {
    int flat = t + q * 256;            // 512 chunks of 4 elems (8*256/4)
    int i = flat >> 6, cj = flat & 63;
    short4 v = *(const short4*)(X + (size_t)(i0 + i) * D + cj * 4);
    xs[i * DP + cj * 4 + 0] = b2f((unsigned short)v.x);
    xs[i * DP + cj * 4 + 1] = b2f((unsigned short)v.y);
    xs[i * DP + cj * 4 + 2] = b2f((unsigned short)v.z);
    xs[i * DP + cj * 4 + 3] = b2f((unsigned short)v.w);
  }
  __syncthreads();

  {  // agg: 1 i per pass, h = t>>6, jg = t&63
    int h = t >> 6, jg = t & 63;
    for (int i = 0; i < 8; ++i) {
      float a0 = 0.f, a1 = 0.f, a2 = 0.f, a3 = 0.f;
      const unsigned short* nbp = NB + (size_t)(i0 + i) * 16 * D + jg * 4;
#pragma unroll
      for (int s = 0; s < 16; ++s) {
        short4 v = *(const short4*)(nbp + (size_t)s * D);
        float wv = al[(i * 4 + h) * 16 + s];
        a0 = fmaf(wv, b2f((unsigned short)v.x), a0);
        a1 = fmaf(wv, b2f((unsigned short)v.y), a1);
        a2 = fmaf(wv, b2f((unsigned short)v.z), a2);
        a3 = fmaf(wv, b2f((unsigned short)v.w), a3);
      }
      float4 av = {a0, a1, a2, a3};
      *(float4*)&agg[(i * 4 + h) * DP + jg * 4] = av;
    }
  }
  __syncthreads();

  {  // out: i = t>>5 (8 i's), 2 cols per thread per head
    const int i = t >> 5, ob = (t & 31) * 2;
    float acc[4][2];
#pragma unroll
    for (int h = 0; h < 4; ++h) { acc[h][0] = 0.f; acc[h][1] = 0.f; }
#pragma unroll 2
    for (int j = 0; j < D; ++j) {
      float xv = xs[i * DP + j];
#pragma unroll
      for (int h = 0; h < 4; ++h) {
        float av = agg[(i * 4 + h) * DP + j];
        float2 wx = *(const float2*)(Wx + ((size_t)h * D + j) * 64 + ob);
        float2 wn = *(const float2*)(Wn + ((size_t)h * D + j) * 64 + ob);
        acc[h][0] = fmaf(xv, wx.x, fmaf(av, wn.x, acc[h][0]));
        acc[h][1] = fmaf(xv, wx.y, fmaf(av, wn.y, acc[h][1]));
      }
    }
#pragma unroll
    for (int h = 0; h < 4; ++h) {
      float r0 = fmaxf(acc[h][0], 0.f), r1 = fmaxf(acc[h][1], 0.f);
      if (OUTB) {
        ushort2 rb = { f2b(r0), f2b(r1) };
        *(ushort2*)((unsigned short*)outv + (size_t)(i0 + i) * 256 + h * 64 + ob) = rb;
      } else {
        float2 rf = {r0, r1};
        *(float2*)((float*)outv + (size_t)(i0 + i) * 256 + h * 64 + ob) = rf;
      }
    }
  }
}

// ---------------------------------------------------------------------------
extern "C" void kernel_launch(void* const* d_in, const int* in_sizes, int n_in,
                              void* d_out, int out_size, void* d_ws, size_t ws_size,
                              hipStream_t stream) {
  (void)in_sizes; (void)n_in; (void)out_size; (void)ws_size;
  const int*   ids   = (const int*)d_in[0];
  const float* feats = (const float*)d_in[1];
  const int*   adjs  = (const int*)d_in[2];
  const float* Wp    = (const float*)d_in[3];
  const float* Wa1_0 = (const float*)d_in[4];
  const float* wa2_0 = (const float*)d_in[5];
  const float* Wx_0  = (const float*)d_in[6];
  const float* Wn_0  = (const float*)d_in[7];
  const float* Wa1_1 = (const float*)d_in[8];
  const float* wa2_1 = (const float*)d_in[9];
  const float* Wx_1  = (const float*)d_in[10];
  const float* Wn_1  = (const float*)d_in[11];
  float* out = (float*)d_out;

  char* ws = (char*)d_ws;
  size_t off = 0;
  auto alloc = [&](size_t bytes) { char* p = ws + off; off += (bytes + 255) & ~(size_t)255; return p; };
  int*            nodes = (int*)alloc(139776 * 4);
  unsigned short* Pb    = (unsigned short*)alloc((size_t)139776 * 128 * 2);
  float*          T     = (float*)alloc((size_t)8192 * 512 * 4);
  float*          AL    = (float*)alloc((size_t)8192 * 64 * 4);
  unsigned short* NF1b  = (unsigned short*)alloc((size_t)8192 * 256 * 2);
  unsigned short* NF0b  = (unsigned short*)alloc((size_t)512 * 256 * 2);
  unsigned short* Wpt   = (unsigned short*)alloc(16384 * 2);
  unsigned short* WT0   = (unsigned short*)alloc(262144 * 2);
  unsigned short* WT1   = (unsigned short*)alloc(524288 * 2);

  transcast_kernel<<<3136, 256, 0, stream>>>(Wp, Wa1_0, Wa1_1, Wpt, WT0, WT1);

  for (int mp = 0; mp < 2; ++mp) {
    const int* adj = adjs + (size_t)mp * 200000 * 32;
    const float* w2_0 = wa2_0 + (size_t)mp * 4 * 128;
    const float* wx_0 = Wx_0  + (size_t)mp * 4 * 128 * 64;
    const float* wn_0 = Wn_0  + (size_t)mp * 4 * 128 * 64;
    const float* w2_1 = wa2_1 + (size_t)mp * 4 * 128;
    const float* wx_1 = Wx_1  + (size_t)mp * 4 * 256 * 64;
    const float* wn_1 = Wn_1  + (size_t)mp * 4 * 256 * 64;
    const unsigned short* WT0_top = WT0 + ((size_t)mp * 2 + 0) * 4 * 128 * 128;
    const unsigned short* WT0_bot = WT0 + ((size_t)mp * 2 + 1) * 4 * 128 * 128;
    const unsigned short* WT1_top = WT1 + ((size_t)mp * 2 + 0) * 4 * 128 * 256;
    const unsigned short* WT1_bot = WT1 + ((size_t)mp * 2 + 1) * 4 * 128 * 256;

    unsigned key0[2], key1[2];
    for (int li = 0; li < 2; ++li) {
      unsigned K0, K1;
      tf2x32(0u, 42u, 0u, (unsigned)(mp * 16 + li), K0, K1);
      tf2x32(K0, K1, 0u, 1u, key0[li], key1[li]);  // split child 1
    }

    hipMemcpyAsync(nodes, ids, 512 * sizeof(int), hipMemcpyDeviceToDevice, stream);
    frontier_kernel<<<32, 256, 0, stream>>>(adj, ids, nodes + 512, 8192, key0[0], key1[0]);
    frontier_kernel<<<512, 256, 0, stream>>>(adj, nodes + 512, nodes + 8704, 131072, key0[1], key1[1]);

    // prep: Pb = bf16( feats[nodes] @ Wp )  [139776,128]
    mfma_gemm<0, true><<<dim3(1092, 1), 256, 0, stream>>>(
        feats, nodes, Wpt, nullptr, nullptr, Pb, nullptr, 128, 128);

    const unsigned short* Pb0 = Pb;
    const unsigned short* Pb1 = Pb + (size_t)512 * 128;
    const unsigned short* Pb2 = Pb + (size_t)8704 * 128;

    // ---- L0 agg B: x=Pb1 (8192), nb=Pb2 (131072) -> NF1b
    mfma_gemm<1, false><<<dim3(64, 4), 256, 0, stream>>>(
        Pb1, nullptr, WT0_top, nullptr, nullptr, T, nullptr, 128, 512);
    mfma_gemm<2, false><<<dim3(1024, 4), 256, 0, stream>>>(
        Pb2, nullptr, WT0_bot, T, w2_0, nullptr, AL, 128, 0);
    out128_kernel<true><<<512, 256, 0, stream>>>(Pb1, Pb2, AL, wx_0, wn_0, NF1b);

    // ---- L0 agg A: x=Pb0 (512), nb=Pb1 (8192) -> NF0b
    mfma_gemm<1, false><<<dim3(4, 4), 256, 0, stream>>>(
        Pb0, nullptr, WT0_top, nullptr, nullptr, T, nullptr, 128, 512);
    mfma_gemm<2, false><<<dim3(64, 4), 256, 0, stream>>>(
        Pb1, nullptr, WT0_bot, T, w2_0, nullptr, AL, 128, 0);
    out128_kernel<true><<<32, 256, 0, stream>>>(Pb0, Pb1, AL, wx_0, wn_0, NF0b);

    // ---- L1: x=NF0b (512), nb=NF1b (8192) -> d_out[mp] fp32
    mfma_gemm<1, false><<<dim3(4, 4), 256, 0, stream>>>(
        NF0b, nullptr, WT1_top, nullptr, nullptr, T, nullptr, 256, 512);
    mfma_gemm<2, false><<<dim3(64, 4), 256, 0, stream>>>(
        NF1b, nullptr, WT1_bot, T, w2_1, nullptr, AL, 256, 0);
    out256_kernel<false><<<64, 256, 0, stream>>>(NF0b, NF1b, AL, wx_1, wn_1,
                                                 out + (size_t)mp * 512 * 256);
  }
}

// Round 5
// 487.647 us; speedup vs baseline: 2.7743x; 1.7770x over previous
//
#include <hip/hip_runtime.h>
#include <math.h>

// ---------------------------------------------------------------------------
// GraphSAGE-attention forward (round 5: MFMA everywhere + latency-bound tail
// kernels replaced by AGG (VALU, high-grid) + OUTG (MFMA GEMM)).
// RNG verified R3: partitionable threefry, bits = o0^o1, split child (0,1).
// C/D layout (m89): col = lane&15, row = (lane>>4)*4 + reg.
// A/B frag: lane l holds 8 contiguous k at row/col = l&15, k0 = (l>>4)*8.
// ---------------------------------------------------------------------------

typedef __attribute__((ext_vector_type(8))) short bf16x8;
typedef __attribute__((ext_vector_type(4))) float f32x4;

__device__ __forceinline__ float b2f(unsigned short u) {
  union { unsigned u; float f; } c; c.u = ((unsigned)u) << 16; return c.f;
}
__device__ __forceinline__ unsigned short f2b(float f) {
  union { float f; unsigned u; } c; c.f = f;
  return (unsigned short)((c.u + 0x7FFFu + ((c.u >> 16) & 1u)) >> 16);
}

__host__ __device__ __forceinline__ void tf2x32(unsigned k0, unsigned k1,
                                                unsigned x0, unsigned x1,
                                                unsigned& o0, unsigned& o1) {
  const unsigned ks2 = k0 ^ k1 ^ 0x1BD11BDAu;
  unsigned v0 = x0 + k0, v1 = x1 + k1;
#define TFR(r) { v0 += v1; v1 = (v1 << (r)) | (v1 >> (32 - (r))); v1 ^= v0; }
  TFR(13) TFR(15) TFR(26) TFR(6)
  v0 += k1;  v1 += ks2 + 1u;
  TFR(17) TFR(29) TFR(16) TFR(24)
  v0 += ks2; v1 += k0 + 2u;
  TFR(13) TFR(15) TFR(26) TFR(6)
  v0 += k0;  v1 += k1 + 3u;
  TFR(17) TFR(29) TFR(16) TFR(24)
  v0 += k1;  v1 += ks2 + 4u;
  TFR(13) TFR(15) TFR(26) TFR(6)
  v0 += ks2; v1 += k0 + 5u;
#undef TFR
  o0 = v0; o1 = v1;
}

__global__ void frontier_kernel(const int* __restrict__ adj,
                                const int* __restrict__ src,
                                int* __restrict__ dst,
                                int n, unsigned k0, unsigned k1) {
  int idx = blockIdx.x * blockDim.x + threadIdx.x;
  if (idx >= n) return;
  unsigned y0, y1;
  tf2x32(k0, k1, 0u, (unsigned)idx, y0, y1);
  int col = (int)((y0 ^ y1) & 31u);
  int parent = src[idx >> 4];
  dst[idx] = adj[(size_t)parent * 32 + col];
}

// ---------------------------------------------------------------------------
// transcast: bf16 transposed weights, linear ranges:
//  [0)        Wpt  [128c][128k]                          16384
//  [16384)    WT0  [mp][half][h][128c][128k]            262144
//  [278528)   WT1  [mp][half][h][128c][256k]            524288
//  [802816)   WXT0 [mp][h][64o][128k]                    65536
//  [868352)   WNT0 [mp][h][64o][128k]                    65536
//  [933888)   WXT1 [mp][h][64o][256k]                   131072
//  [1064960)  WNT1 [mp][h][64o][256k]                   131072   total 1196032
// ---------------------------------------------------------------------------
__global__ void transcast_kernel(const float* __restrict__ Wp,
                                 const float* __restrict__ Wa1_0,
                                 const float* __restrict__ Wa1_1,
                                 const float* __restrict__ Wx_0,
                                 const float* __restrict__ Wn_0,
                                 const float* __restrict__ Wx_1,
                                 const float* __restrict__ Wn_1,
                                 unsigned short* __restrict__ Wpt) {
  int o = blockIdx.x * 256 + threadIdx.x;
  if (o >= 1196032) return;
  float v;
  if (o < 16384) {
    int k = o & 127, c = o >> 7;
    v = Wp[k * 128 + c];
  } else if (o < 278528) {
    int o2 = o - 16384;
    int k = o2 & 127, c = (o2 >> 7) & 127, h = (o2 >> 14) & 3,
        half = (o2 >> 16) & 1, mpi = o2 >> 17;
    v = Wa1_0[(((size_t)(mpi * 4 + h) * 256) + half * 128 + k) * 128 + c];
  } else if (o < 802816) {
    int o3 = o - 278528;
    int k = o3 & 255, c = (o3 >> 8) & 127, h = (o3 >> 15) & 3,
        half = (o3 >> 17) & 1, mpi = o3 >> 18;
    v = Wa1_1[(((size_t)(mpi * 4 + h) * 512) + half * 256 + k) * 128 + c];
  } else if (o < 868352) {
    int o4 = o - 802816;
    int k = o4 & 127, oo = (o4 >> 7) & 63, h = (o4 >> 13) & 3, mpi = o4 >> 15;
    v = Wx_0[(((size_t)(mpi * 4 + h) * 128) + k) * 64 + oo];
  } else if (o < 933888) {
    int o4 = o - 868352;
    int k = o4 & 127, oo = (o4 >> 7) & 63, h = (o4 >> 13) & 3, mpi = o4 >> 15;
    v = Wn_0[(((size_t)(mpi * 4 + h) * 128) + k) * 64 + oo];
  } else if (o < 1064960) {
    int o5 = o - 933888;
    int k = o5 & 255, oo = (o5 >> 8) & 63, h = (o5 >> 14) & 3, mpi = o5 >> 16;
    v = Wx_1[(((size_t)(mpi * 4 + h) * 256) + k) * 64 + oo];
  } else {
    int o5 = o - 1064960;
    int k = o5 & 255, oo = (o5 >> 8) & 63, h = (o5 >> 14) & 3, mpi = o5 >> 16;
    v = Wn_1[(((size_t)(mpi * 4 + h) * 256) + k) * 64 + oo];
  }
  Wpt[o] = f2b(v);
}

// ---------------------------------------------------------------------------
// MFMA GEMM (prep / T): block = 128 rows x 128 cols, 4 waves x 32 rows.
// MODE 0: bf16 C [M][ldc] (prep: A fp32 + gather)   MODE 1: f32 C, col hb*128
// ---------------------------------------------------------------------------
template <int MODE, bool A_F32>
__global__ __launch_bounds__(256) void mfma_gemm(
    const void* __restrict__ Av, const int* __restrict__ gather,
    const unsigned short* __restrict__ WT, void* __restrict__ Cv,
    int K, int ldc) {
  const int t = threadIdx.x;
  const int w = t >> 6, l = t & 63;
  const int lr = l & 15, lg = l >> 4;
  const int hb = blockIdx.y;
  const int rbase = blockIdx.x * 128 + w * 32;

  const unsigned short* Wb = WT + (size_t)hb * 128 * K;
  f32x4 acc[2][8] = {};

  int arow[2];
#pragma unroll
  for (int mg = 0; mg < 2; ++mg) {
    int row = rbase + mg * 16 + lr;
    arow[mg] = gather ? gather[row] : row;
  }
  const float* Af = (const float*)Av;
  const unsigned short* Ab = (const unsigned short*)Av;
  const int nks = K >> 5;

  for (int ks = 0; ks < nks; ++ks) {
    const int koff = ks * 32 + lg * 8;
    bf16x8 a[2], b[8];
#pragma unroll
    for (int mg = 0; mg < 2; ++mg) {
      if (A_F32) {
        const float* p = Af + (size_t)arow[mg] * K + koff;
        float4 v0 = *(const float4*)p;
        float4 v1 = *(const float4*)(p + 4);
        union { short s[8]; bf16x8 v; } u;
        u.s[0] = (short)f2b(v0.x); u.s[1] = (short)f2b(v0.y);
        u.s[2] = (short)f2b(v0.z); u.s[3] = (short)f2b(v0.w);
        u.s[4] = (short)f2b(v1.x); u.s[5] = (short)f2b(v1.y);
        u.s[6] = (short)f2b(v1.z); u.s[7] = (short)f2b(v1.w);
        a[mg] = u.v;
      } else {
        a[mg] = *(const bf16x8*)(Ab + (size_t)arow[mg] * K + koff);
      }
    }
#pragma unroll
    for (int f = 0; f < 8; ++f)
      b[f] = *(const bf16x8*)(Wb + (size_t)(f * 16 + lr) * K + koff);
#pragma unroll
    for (int mg = 0; mg < 2; ++mg)
#pragma unroll
      for (int f = 0; f < 8; ++f)
        acc[mg][f] = __builtin_amdgcn_mfma_f32_16x16x32_bf16(a[mg], b[f], acc[mg][f], 0, 0, 0);
  }

  if (MODE == 0) {
    unsigned short* Cb = (unsigned short*)Cv;
#pragma unroll
    for (int mg = 0; mg < 2; ++mg)
#pragma unroll
      for (int f = 0; f < 8; ++f)
#pragma unroll
        for (int r = 0; r < 4; ++r)
          Cb[(size_t)(rbase + mg * 16 + lg * 4 + r) * ldc + f * 16 + lr] =
              f2b(acc[mg][f][r]);
  } else {
    float* Cf = (float*)Cv;
#pragma unroll
    for (int mg = 0; mg < 2; ++mg)
#pragma unroll
      for (int f = 0; f < 8; ++f)
#pragma unroll
        for (int r = 0; r < 4; ++r)
          Cf[(size_t)(rbase + mg * 16 + lg * 4 + r) * ldc + hb * 128 + f * 16 + lr] =
              acc[mg][f][r];
  }
}

// ---------------------------------------------------------------------------
// AGGSC: block = 32 NB rows (2 m-rows x 16 samples), 4 waves = 4 heads.
// U = nb @ Wa1_bot (MFMA), score = sum_c tanh(U+T)*wa2, softmax_s -> AL.
// ---------------------------------------------------------------------------
__global__ __launch_bounds__(256) void aggsc_mfma(
    const unsigned short* __restrict__ NB,   // [m*16][K] bf16
    const float* __restrict__ Tb,            // [m][512]
    const unsigned short* __restrict__ WTbot,// [4][128][K] bf16
    const float* __restrict__ wa2,           // [4][128]
    float* __restrict__ AL,                  // [m][4][16]
    int K) {
  const int t = threadIdx.x;
  const int hb = t >> 6, l = t & 63;
  const int lr = l & 15, lg = l >> 4;
  const int rbase = blockIdx.x * 32;

  const unsigned short* Wb = WTbot + (size_t)hb * 128 * K;
  f32x4 acc[2][8] = {};
  const int nks = K >> 5;

  for (int ks = 0; ks < nks; ++ks) {
    const int koff = ks * 32 + lg * 8;
    bf16x8 a[2], b[8];
#pragma unroll
    for (int mg = 0; mg < 2; ++mg)
      a[mg] = *(const bf16x8*)(NB + (size_t)(rbase + mg * 16 + lr) * K + koff);
#pragma unroll
    for (int f = 0; f < 8; ++f)
      b[f] = *(const bf16x8*)(Wb + (size_t)(f * 16 + lr) * K + koff);
#pragma unroll
    for (int mg = 0; mg < 2; ++mg)
#pragma unroll
      for (int f = 0; f < 8; ++f)
        acc[mg][f] = __builtin_amdgcn_mfma_f32_16x16x32_bf16(a[mg], b[f], acc[mg][f], 0, 0, 0);
  }

  float w2[8];
#pragma unroll
  for (int f = 0; f < 8; ++f) w2[f] = wa2[hb * 128 + f * 16 + lr];
#pragma unroll
  for (int mg = 0; mg < 2; ++mg) {
    const int i = blockIdx.x * 2 + mg;
    float tv[8];
#pragma unroll
    for (int f = 0; f < 8; ++f)
      tv[f] = Tb[(size_t)i * 512 + hb * 128 + f * 16 + lr];
    float sc[4];
#pragma unroll
    for (int r = 0; r < 4; ++r) {
      float s = 0.f;
#pragma unroll
      for (int f = 0; f < 8; ++f)
        s += tanhf(acc[mg][f][r] + tv[f]) * w2[f];
      s += __shfl_xor(s, 1); s += __shfl_xor(s, 2);
      s += __shfl_xor(s, 4); s += __shfl_xor(s, 8);
      sc[r] = s;
    }
    float mx = fmaxf(fmaxf(sc[0], sc[1]), fmaxf(sc[2], sc[3]));
    mx = fmaxf(mx, __shfl_xor(mx, 16));
    mx = fmaxf(mx, __shfl_xor(mx, 32));
    float e0 = expf(sc[0] - mx), e1 = expf(sc[1] - mx);
    float e2 = expf(sc[2] - mx), e3 = expf(sc[3] - mx);
    float sum = e0 + e1 + e2 + e3;
    sum += __shfl_xor(sum, 16); sum += __shfl_xor(sum, 32);
    float inv = 1.f / sum;
    if (lr == 0) {
      float4 o4 = { e0 * inv, e1 * inv, e2 * inv, e3 * inv };
      *(float4*)(AL + (size_t)i * 64 + hb * 16 + lg * 4) = o4;
    }
  }
}

// ---------------------------------------------------------------------------
// AGG: AG[i][h][d] = sum_s alpha[i][h][s] * nb[i][s][d]  (bf16 out)
// block: IB = 256/(D/4) i-rows; thread computes 4 cols for all 4 heads.
// ---------------------------------------------------------------------------
template <int D>
__global__ __launch_bounds__(256) void agg_kernel(
    const unsigned short* __restrict__ NB, const float* __restrict__ alpha,
    unsigned short* __restrict__ AG) {
  constexpr int JT = D / 4;
  constexpr int IB = 256 / JT;
  const int t = threadIdx.x;
  const int i0 = blockIdx.x * IB;
  __shared__ float al[IB * 64];
  if (t < IB * 16) ((float4*)al)[t] = ((const float4*)(alpha + (size_t)i0 * 64))[t];
  __syncthreads();
  const int il = t / JT, jg = t % JT;
  const int i = i0 + il;
  float a[4][4] = {};
  const unsigned short* nbp = NB + (size_t)i * 16 * D + jg * 4;
#pragma unroll
  for (int s = 0; s < 16; ++s) {
    short4 v = *(const short4*)(nbp + (size_t)s * D);
    float v0 = b2f((unsigned short)v.x), v1 = b2f((unsigned short)v.y);
    float v2 = b2f((unsigned short)v.z), v3 = b2f((unsigned short)v.w);
#pragma unroll
    for (int h = 0; h < 4; ++h) {
      float wv = al[il * 64 + h * 16 + s];
      a[h][0] = fmaf(wv, v0, a[h][0]); a[h][1] = fmaf(wv, v1, a[h][1]);
      a[h][2] = fmaf(wv, v2, a[h][2]); a[h][3] = fmaf(wv, v3, a[h][3]);
    }
  }
#pragma unroll
  for (int h = 0; h < 4; ++h) {
    ushort4 o4 = { f2b(a[h][0]), f2b(a[h][1]), f2b(a[h][2]), f2b(a[h][3]) };
    *(ushort4*)(AG + ((size_t)i * 4 + h) * D + jg * 4) = o4;
  }
}

// ---------------------------------------------------------------------------
// OUTG: out[m, hb*64+c] = relu( x @ Wx[hb] + agg[hb] @ Wn[hb] )  (MFMA)
// block = 128 rows x 64 cols (head hb), 4 waves x 32 rows.
// ---------------------------------------------------------------------------
template <int DX, bool OUTB>
__global__ __launch_bounds__(256) void outg_kernel(
    const unsigned short* __restrict__ Xb,   // [M][DX]
    const unsigned short* __restrict__ AG,   // [M][4][DX]
    const unsigned short* __restrict__ WXT,  // [4][64][DX]
    const unsigned short* __restrict__ WNT,  // [4][64][DX]
    void* __restrict__ outv) {               // [M][256]
  const int t = threadIdx.x;
  const int w = t >> 6, l = t & 63;
  const int lr = l & 15, lg = l >> 4;
  const int hb = blockIdx.y;
  const int rbase = blockIdx.x * 128 + w * 32;
  f32x4 acc[2][4] = {};
  constexpr int nks = DX >> 5;

#pragma unroll
  for (int ks = 0; ks < nks; ++ks) {
    const int koff = ks * 32 + lg * 8;
    bf16x8 a[2], b[4];
#pragma unroll
    for (int mg = 0; mg < 2; ++mg)
      a[mg] = *(const bf16x8*)(Xb + (size_t)(rbase + mg * 16 + lr) * DX + koff);
#pragma unroll
    for (int f = 0; f < 4; ++f)
      b[f] = *(const bf16x8*)(WXT + (size_t)(hb * 64 + f * 16 + lr) * DX + koff);
#pragma unroll
    for (int mg = 0; mg < 2; ++mg)
#pragma unroll
      for (int f = 0; f < 4; ++f)
        acc[mg][f] = __builtin_amdgcn_mfma_f32_16x16x32_bf16(a[mg], b[f], acc[mg][f], 0, 0, 0);
  }
#pragma unroll
  for (int ks = 0; ks < nks; ++ks) {
    const int koff = ks * 32 + lg * 8;
    bf16x8 a[2], b[4];
#pragma unroll
    for (int mg = 0; mg < 2; ++mg)
      a[mg] = *(const bf16x8*)(AG + ((size_t)(rbase + mg * 16 + lr) * 4 + hb) * DX + koff);
#pragma unroll
    for (int f = 0; f < 4; ++f)
      b[f] = *(const bf16x8*)(WNT + (size_t)(hb * 64 + f * 16 + lr) * DX + koff);
#pragma unroll
    for (int mg = 0; mg < 2; ++mg)
#pragma unroll
      for (int f = 0; f < 4; ++f)
        acc[mg][f] = __builtin_amdgcn_mfma_f32_16x16x32_bf16(a[mg], b[f], acc[mg][f], 0, 0, 0);
  }

#pragma unroll
  for (int mg = 0; mg < 2; ++mg)
#pragma unroll
    for (int f = 0; f < 4; ++f)
#pragma unroll
      for (int r = 0; r < 4; ++r) {
        float v = fmaxf(acc[mg][f][r], 0.f);
        size_t idx = (size_t)(rbase + mg * 16 + lg * 4 + r) * 256 + hb * 64 + f * 16 + lr;
        if (OUTB) ((unsigned short*)outv)[idx] = f2b(v);
        else      ((float*)outv)[idx] = v;
      }
}

// ---------------------------------------------------------------------------
extern "C" void kernel_launch(void* const* d_in, const int* in_sizes, int n_in,
                              void* d_out, int out_size, void* d_ws, size_t ws_size,
                              hipStream_t stream) {
  (void)in_sizes; (void)n_in; (void)out_size; (void)ws_size;
  const int*   ids   = (const int*)d_in[0];
  const float* feats = (const float*)d_in[1];
  const int*   adjs  = (const int*)d_in[2];
  const float* Wp    = (const float*)d_in[3];
  const float* Wa1_0 = (const float*)d_in[4];
  const float* wa2_0 = (const float*)d_in[5];
  const float* Wx_0  = (const float*)d_in[6];
  const float* Wn_0  = (const float*)d_in[7];
  const float* Wa1_1 = (const float*)d_in[8];
  const float* wa2_1 = (const float*)d_in[9];
  const float* Wx_1  = (const float*)d_in[10];
  const float* Wn_1  = (const float*)d_in[11];
  float* out = (float*)d_out;

  char* ws = (char*)d_ws;
  size_t off = 0;
  auto alloc = [&](size_t bytes) { char* p = ws + off; off += (bytes + 255) & ~(size_t)255; return p; };
  int*            nodes = (int*)alloc(139776 * 4);
  unsigned short* Pb    = (unsigned short*)alloc((size_t)139776 * 128 * 2);
  float*          T     = (float*)alloc((size_t)8192 * 512 * 4);
  float*          AL    = (float*)alloc((size_t)8192 * 64 * 4);
  unsigned short* AG    = (unsigned short*)alloc((size_t)8192 * 4 * 256 * 2);
  unsigned short* NF1b  = (unsigned short*)alloc((size_t)8192 * 256 * 2);
  unsigned short* NF0b  = (unsigned short*)alloc((size_t)512 * 256 * 2);
  unsigned short* WB    = (unsigned short*)alloc((size_t)1196032 * 2);

  unsigned short* Wpt  = WB;
  unsigned short* WT0  = WB + 16384;
  unsigned short* WT1  = WB + 278528;
  unsigned short* WXT0 = WB + 802816;
  unsigned short* WNT0 = WB + 868352;
  unsigned short* WXT1 = WB + 933888;
  unsigned short* WNT1 = WB + 1064960;

  transcast_kernel<<<4672, 256, 0, stream>>>(Wp, Wa1_0, Wa1_1, Wx_0, Wn_0,
                                             Wx_1, Wn_1, WB);

  for (int mp = 0; mp < 2; ++mp) {
    const int* adj = adjs + (size_t)mp * 200000 * 32;
    const float* w2_0 = wa2_0 + (size_t)mp * 4 * 128;
    const float* w2_1 = wa2_1 + (size_t)mp * 4 * 128;
    const unsigned short* WT0_top = WT0 + (size_t)mp * 2 * 65536;
    const unsigned short* WT0_bot = WT0 + ((size_t)mp * 2 + 1) * 65536;
    const unsigned short* WT1_top = WT1 + (size_t)mp * 2 * 131072;
    const unsigned short* WT1_bot = WT1 + ((size_t)mp * 2 + 1) * 131072;
    const unsigned short* wxt0 = WXT0 + (size_t)mp * 32768;
    const unsigned short* wnt0 = WNT0 + (size_t)mp * 32768;
    const unsigned short* wxt1 = WXT1 + (size_t)mp * 65536;
    const unsigned short* wnt1 = WNT1 + (size_t)mp * 65536;

    unsigned key0[2], key1[2];
    for (int li = 0; li < 2; ++li) {
      unsigned K0, K1;
      tf2x32(0u, 42u, 0u, (unsigned)(mp * 16 + li), K0, K1);
      tf2x32(K0, K1, 0u, 1u, key0[li], key1[li]);
    }

    hipMemcpyAsync(nodes, ids, 512 * sizeof(int), hipMemcpyDeviceToDevice, stream);
    frontier_kernel<<<32, 256, 0, stream>>>(adj, ids, nodes + 512, 8192, key0[0], key1[0]);
    frontier_kernel<<<512, 256, 0, stream>>>(adj, nodes + 512, nodes + 8704, 131072, key0[1], key1[1]);

    mfma_gemm<0, true><<<dim3(1092, 1), 256, 0, stream>>>(
        feats, nodes, Wpt, Pb, 128, 128);

    const unsigned short* Pb0 = Pb;
    const unsigned short* Pb1 = Pb + (size_t)512 * 128;
    const unsigned short* Pb2 = Pb + (size_t)8704 * 128;

    // ---- L0 agg B: x=Pb1 (8192), nb=Pb2 (131072) -> NF1b
    mfma_gemm<1, false><<<dim3(64, 4), 256, 0, stream>>>(
        Pb1, nullptr, WT0_top, T, 128, 512);
    aggsc_mfma<<<4096, 256, 0, stream>>>(Pb2, T, WT0_bot, w2_0, AL, 128);
    agg_kernel<128><<<1024, 256, 0, stream>>>(Pb2, AL, AG);
    outg_kernel<128, true><<<dim3(64, 4), 256, 0, stream>>>(
        Pb1, AG, wxt0, wnt0, NF1b);

    // ---- L0 agg A: x=Pb0 (512), nb=Pb1 (8192) -> NF0b
    mfma_gemm<1, false><<<dim3(4, 4), 256, 0, stream>>>(
        Pb0, nullptr, WT0_top, T, 128, 512);
    aggsc_mfma<<<256, 256, 0, stream>>>(Pb1, T, WT0_bot, w2_0, AL, 128);
    agg_kernel<128><<<64, 256, 0, stream>>>(Pb1, AL, AG);
    outg_kernel<128, true><<<dim3(4, 4), 256, 0, stream>>>(
        Pb0, AG, wxt0, wnt0, NF0b);

    // ---- L1: x=NF0b (512), nb=NF1b (8192) -> d_out[mp] fp32
    mfma_gemm<1, false><<<dim3(4, 4), 256, 0, stream>>>(
        NF0b, nullptr, WT1_top, T, 256, 512);
    aggsc_mfma<<<256, 256, 0, stream>>>(NF1b, T, WT1_bot, w2_1, AL, 256);
    agg_kernel<256><<<128, 256, 0, stream>>>(NF1b, AL, AG);
    outg_kernel<256, false><<<dim3(4, 4), 256, 0, stream>>>(
        NF0b, AG, wxt1, wnt1, out + (size_t)mp * 512 * 256);
  }
}

// Round 6
// 417.373 us; speedup vs baseline: 3.2414x; 1.1684x over previous
//
#include <hip/hip_runtime.h>
#include <math.h>

// ---------------------------------------------------------------------------
// GraphSAGE-attention forward (round 6: fast-tanh epilogue + AGG fused into
// aggsc; agg_kernel and AL buffer deleted).
// RNG verified R3: partitionable threefry, bits = o0^o1, split child (0,1).
// C/D layout (m89): col = lane&15, row = (lane>>4)*4 + reg.
// A/B frag: lane l holds 8 contiguous k at row/col = l&15, k0 = (l>>4)*8.
// ---------------------------------------------------------------------------

typedef __attribute__((ext_vector_type(8))) short bf16x8;
typedef __attribute__((ext_vector_type(4))) float f32x4;

__device__ __forceinline__ float b2f(unsigned short u) {
  union { unsigned u; float f; } c; c.u = ((unsigned)u) << 16; return c.f;
}
__device__ __forceinline__ unsigned short f2b(float f) {
  union { float f; unsigned u; } c; c.f = f;
  return (unsigned short)((c.u + 0x7FFFu + ((c.u >> 16) & 1u)) >> 16);
}

// tanh(x) = 1 - 2/(1+e^{2x}); e^{2x} = 2^{x*2log2(e)}. v_exp_f32 + v_rcp_f32.
// x->+inf: exp=inf, rcp=0 -> 1.  x->-inf: exp=0, rcp=1 -> -1.  No NaN path.
__device__ __forceinline__ float fast_tanh(float x) {
  float y = x * 2.8853900817779268f;
  float z; asm("v_exp_f32 %0, %1" : "=v"(z) : "v"(y));
  float zp1 = z + 1.f;
  float w; asm("v_rcp_f32 %0, %1" : "=v"(w) : "v"(zp1));
  return fmaf(-2.f, w, 1.f);
}

__host__ __device__ __forceinline__ void tf2x32(unsigned k0, unsigned k1,
                                                unsigned x0, unsigned x1,
                                                unsigned& o0, unsigned& o1) {
  const unsigned ks2 = k0 ^ k1 ^ 0x1BD11BDAu;
  unsigned v0 = x0 + k0, v1 = x1 + k1;
#define TFR(r) { v0 += v1; v1 = (v1 << (r)) | (v1 >> (32 - (r))); v1 ^= v0; }
  TFR(13) TFR(15) TFR(26) TFR(6)
  v0 += k1;  v1 += ks2 + 1u;
  TFR(17) TFR(29) TFR(16) TFR(24)
  v0 += ks2; v1 += k0 + 2u;
  TFR(13) TFR(15) TFR(26) TFR(6)
  v0 += k0;  v1 += k1 + 3u;
  TFR(17) TFR(29) TFR(16) TFR(24)
  v0 += k1;  v1 += ks2 + 4u;
  TFR(13) TFR(15) TFR(26) TFR(6)
  v0 += ks2; v1 += k0 + 5u;
#undef TFR
  o0 = v0; o1 = v1;
}

__global__ void frontier_kernel(const int* __restrict__ adj,
                                const int* __restrict__ src,
                                int* __restrict__ dst,
                                int n, unsigned k0, unsigned k1) {
  int idx = blockIdx.x * blockDim.x + threadIdx.x;
  if (idx >= n) return;
  unsigned y0, y1;
  tf2x32(k0, k1, 0u, (unsigned)idx, y0, y1);
  int col = (int)((y0 ^ y1) & 31u);
  int parent = src[idx >> 4];
  dst[idx] = adj[(size_t)parent * 32 + col];
}

// ---------------------------------------------------------------------------
// transcast: bf16 transposed weights, linear ranges (see R5 comment).
// ---------------------------------------------------------------------------
__global__ void transcast_kernel(const float* __restrict__ Wp,
                                 const float* __restrict__ Wa1_0,
                                 const float* __restrict__ Wa1_1,
                                 const float* __restrict__ Wx_0,
                                 const float* __restrict__ Wn_0,
                                 const float* __restrict__ Wx_1,
                                 const float* __restrict__ Wn_1,
                                 unsigned short* __restrict__ Wpt) {
  int o = blockIdx.x * 256 + threadIdx.x;
  if (o >= 1196032) return;
  float v;
  if (o < 16384) {
    int k = o & 127, c = o >> 7;
    v = Wp[k * 128 + c];
  } else if (o < 278528) {
    int o2 = o - 16384;
    int k = o2 & 127, c = (o2 >> 7) & 127, h = (o2 >> 14) & 3,
        half = (o2 >> 16) & 1, mpi = o2 >> 17;
    v = Wa1_0[(((size_t)(mpi * 4 + h) * 256) + half * 128 + k) * 128 + c];
  } else if (o < 802816) {
    int o3 = o - 278528;
    int k = o3 & 255, c = (o3 >> 8) & 127, h = (o3 >> 15) & 3,
        half = (o3 >> 17) & 1, mpi = o3 >> 18;
    v = Wa1_1[(((size_t)(mpi * 4 + h) * 512) + half * 256 + k) * 128 + c];
  } else if (o < 868352) {
    int o4 = o - 802816;
    int k = o4 & 127, oo = (o4 >> 7) & 63, h = (o4 >> 13) & 3, mpi = o4 >> 15;
    v = Wx_0[(((size_t)(mpi * 4 + h) * 128) + k) * 64 + oo];
  } else if (o < 933888) {
    int o4 = o - 868352;
    int k = o4 & 127, oo = (o4 >> 7) & 63, h = (o4 >> 13) & 3, mpi = o4 >> 15;
    v = Wn_0[(((size_t)(mpi * 4 + h) * 128) + k) * 64 + oo];
  } else if (o < 1064960) {
    int o5 = o - 933888;
    int k = o5 & 255, oo = (o5 >> 8) & 63, h = (o5 >> 14) & 3, mpi = o5 >> 16;
    v = Wx_1[(((size_t)(mpi * 4 + h) * 256) + k) * 64 + oo];
  } else {
    int o5 = o - 1064960;
    int k = o5 & 255, oo = (o5 >> 8) & 63, h = (o5 >> 14) & 3, mpi = o5 >> 16;
    v = Wn_1[(((size_t)(mpi * 4 + h) * 256) + k) * 64 + oo];
  }
  Wpt[o] = f2b(v);
}

// ---------------------------------------------------------------------------
// MFMA GEMM (prep / T): block = 128 rows x 128 cols, 4 waves x 32 rows.
// MODE 0: bf16 C [M][ldc] (prep: A fp32 + gather)   MODE 1: f32 C, col hb*128
// ---------------------------------------------------------------------------
template <int MODE, bool A_F32>
__global__ __launch_bounds__(256) void mfma_gemm(
    const void* __restrict__ Av, const int* __restrict__ gather,
    const unsigned short* __restrict__ WT, void* __restrict__ Cv,
    int K, int ldc) {
  const int t = threadIdx.x;
  const int w = t >> 6, l = t & 63;
  const int lr = l & 15, lg = l >> 4;
  const int hb = blockIdx.y;
  const int rbase = blockIdx.x * 128 + w * 32;

  const unsigned short* Wb = WT + (size_t)hb * 128 * K;
  f32x4 acc[2][8] = {};

  int arow[2];
#pragma unroll
  for (int mg = 0; mg < 2; ++mg) {
    int row = rbase + mg * 16 + lr;
    arow[mg] = gather ? gather[row] : row;
  }
  const float* Af = (const float*)Av;
  const unsigned short* Ab = (const unsigned short*)Av;
  const int nks = K >> 5;

  for (int ks = 0; ks < nks; ++ks) {
    const int koff = ks * 32 + lg * 8;
    bf16x8 a[2], b[8];
#pragma unroll
    for (int mg = 0; mg < 2; ++mg) {
      if (A_F32) {
        const float* p = Af + (size_t)arow[mg] * K + koff;
        float4 v0 = *(const float4*)p;
        float4 v1 = *(const float4*)(p + 4);
        union { short s[8]; bf16x8 v; } u;
        u.s[0] = (short)f2b(v0.x); u.s[1] = (short)f2b(v0.y);
        u.s[2] = (short)f2b(v0.z); u.s[3] = (short)f2b(v0.w);
        u.s[4] = (short)f2b(v1.x); u.s[5] = (short)f2b(v1.y);
        u.s[6] = (short)f2b(v1.z); u.s[7] = (short)f2b(v1.w);
        a[mg] = u.v;
      } else {
        a[mg] = *(const bf16x8*)(Ab + (size_t)arow[mg] * K + koff);
      }
    }
#pragma unroll
    for (int f = 0; f < 8; ++f)
      b[f] = *(const bf16x8*)(Wb + (size_t)(f * 16 + lr) * K + koff);
#pragma unroll
    for (int mg = 0; mg < 2; ++mg)
#pragma unroll
      for (int f = 0; f < 8; ++f)
        acc[mg][f] = __builtin_amdgcn_mfma_f32_16x16x32_bf16(a[mg], b[f], acc[mg][f], 0, 0, 0);
  }

  if (MODE == 0) {
    unsigned short* Cb = (unsigned short*)Cv;
#pragma unroll
    for (int mg = 0; mg < 2; ++mg)
#pragma unroll
      for (int f = 0; f < 8; ++f)
#pragma unroll
        for (int r = 0; r < 4; ++r)
          Cb[(size_t)(rbase + mg * 16 + lg * 4 + r) * ldc + f * 16 + lr] =
              f2b(acc[mg][f][r]);
  } else {
    float* Cf = (float*)Cv;
#pragma unroll
    for (int mg = 0; mg < 2; ++mg)
#pragma unroll
      for (int f = 0; f < 8; ++f)
#pragma unroll
        for (int r = 0; r < 4; ++r)
          Cf[(size_t)(rbase + mg * 16 + lg * 4 + r) * ldc + hb * 128 + f * 16 + lr] =
              acc[mg][f][r];
  }
}

// ---------------------------------------------------------------------------
// AGGSC+AGG fused: block = 32 NB rows (2 m-rows x 16 samples), 4 waves = heads.
// U = nb @ Wa1_bot (MFMA); score = sum_c fast_tanh(U+T)*wa2; softmax_s;
// then AG[i][h][:] = sum_s alpha*nb (alpha via LDS, nb re-read from L2).
// ---------------------------------------------------------------------------
__global__ __launch_bounds__(256) void aggsc_mfma(
    const unsigned short* __restrict__ NB,   // [m*16][K] bf16
    const float* __restrict__ Tb,            // [m][512]
    const unsigned short* __restrict__ WTbot,// [4][128][K] bf16
    const float* __restrict__ wa2,           // [4][128]
    unsigned short* __restrict__ AG,         // [m][4][K] bf16
    int K) {
  const int t = threadIdx.x;
  const int hb = t >> 6, l = t & 63;
  const int lr = l & 15, lg = l >> 4;
  const int rbase = blockIdx.x * 32;

  __shared__ float alsh[4][2][16];

  const unsigned short* Wb = WTbot + (size_t)hb * 128 * K;
  f32x4 acc[2][8] = {};
  const int nks = K >> 5;

  for (int ks = 0; ks < nks; ++ks) {
    const int koff = ks * 32 + lg * 8;
    bf16x8 a[2], b[8];
#pragma unroll
    for (int mg = 0; mg < 2; ++mg)
      a[mg] = *(const bf16x8*)(NB + (size_t)(rbase + mg * 16 + lr) * K + koff);
#pragma unroll
    for (int f = 0; f < 8; ++f)
      b[f] = *(const bf16x8*)(Wb + (size_t)(f * 16 + lr) * K + koff);
#pragma unroll
    for (int mg = 0; mg < 2; ++mg)
#pragma unroll
      for (int f = 0; f < 8; ++f)
        acc[mg][f] = __builtin_amdgcn_mfma_f32_16x16x32_bf16(a[mg], b[f], acc[mg][f], 0, 0, 0);
  }

  float w2[8];
#pragma unroll
  for (int f = 0; f < 8; ++f) w2[f] = wa2[hb * 128 + f * 16 + lr];
#pragma unroll
  for (int mg = 0; mg < 2; ++mg) {
    const int i = blockIdx.x * 2 + mg;
    float tv[8];
#pragma unroll
    for (int f = 0; f < 8; ++f)
      tv[f] = Tb[(size_t)i * 512 + hb * 128 + f * 16 + lr];
    float sc[4];
#pragma unroll
    for (int r = 0; r < 4; ++r) {
      float s = 0.f;
#pragma unroll
      for (int f = 0; f < 8; ++f)
        s += fast_tanh(acc[mg][f][r] + tv[f]) * w2[f];
      s += __shfl_xor(s, 1); s += __shfl_xor(s, 2);
      s += __shfl_xor(s, 4); s += __shfl_xor(s, 8);
      sc[r] = s;
    }
    float mx = fmaxf(fmaxf(sc[0], sc[1]), fmaxf(sc[2], sc[3]));
    mx = fmaxf(mx, __shfl_xor(mx, 16));
    mx = fmaxf(mx, __shfl_xor(mx, 32));
    float e0 = expf(sc[0] - mx), e1 = expf(sc[1] - mx);
    float e2 = expf(sc[2] - mx), e3 = expf(sc[3] - mx);
    float sum = e0 + e1 + e2 + e3;
    sum += __shfl_xor(sum, 16); sum += __shfl_xor(sum, 32);
    float inv = 1.f / sum;
    if (lr == 0) {
      alsh[hb][mg][lg * 4 + 0] = e0 * inv;
      alsh[hb][mg][lg * 4 + 1] = e1 * inv;
      alsh[hb][mg][lg * 4 + 2] = e2 * inv;
      alsh[hb][mg][lg * 4 + 3] = e3 * inv;
    }
  }
  __syncthreads();

  // AG phase: wave hb computes AG[i][hb][:] for i = 2b, 2b+1.
  // Lane covers ushort2 chunks at d = l*2 + c*128 (c < K/128).
  const int nch = K >> 7;
#pragma unroll
  for (int mg = 0; mg < 2; ++mg) {
    const int i = blockIdx.x * 2 + mg;
    float al[16];
#pragma unroll
    for (int s = 0; s < 16; ++s) al[s] = alsh[hb][mg][s];
#pragma unroll
    for (int c = 0; c < 2; ++c) {
      if (c >= nch) break;
      const int d = l * 2 + c * 128;
      const unsigned short* nbp = NB + (size_t)(rbase + mg * 16) * K + d;
      float a0 = 0.f, a1 = 0.f;
#pragma unroll
      for (int s = 0; s < 16; ++s) {
        unsigned v = *(const unsigned*)(nbp + (size_t)s * K);
        a0 = fmaf(al[s], b2f((unsigned short)(v & 0xffffu)), a0);
        a1 = fmaf(al[s], b2f((unsigned short)(v >> 16)), a1);
      }
      unsigned o = (unsigned)f2b(a0) | ((unsigned)f2b(a1) << 16);
      *(unsigned*)(AG + ((size_t)i * 4 + hb) * K + d) = o;
    }
  }
}

// ---------------------------------------------------------------------------
// OUTG: out[m, hb*64+c] = relu( x @ Wx[hb] + agg[hb] @ Wn[hb] )  (MFMA)
// block = 128 rows x 64 cols (head hb), 4 waves x 32 rows.
// ---------------------------------------------------------------------------
template <int DX, bool OUTB>
__global__ __launch_bounds__(256) void outg_kernel(
    const unsigned short* __restrict__ Xb,   // [M][DX]
    const unsigned short* __restrict__ AG,   // [M][4][DX]
    const unsigned short* __restrict__ WXT,  // [4][64][DX]
    const unsigned short* __restrict__ WNT,  // [4][64][DX]
    void* __restrict__ outv) {               // [M][256]
  const int t = threadIdx.x;
  const int w = t >> 6, l = t & 63;
  const int lr = l & 15, lg = l >> 4;
  const int hb = blockIdx.y;
  const int rbase = blockIdx.x * 128 + w * 32;
  f32x4 acc[2][4] = {};
  constexpr int nks = DX >> 5;

#pragma unroll
  for (int ks = 0; ks < nks; ++ks) {
    const int koff = ks * 32 + lg * 8;
    bf16x8 a[2], b[4];
#pragma unroll
    for (int mg = 0; mg < 2; ++mg)
      a[mg] = *(const bf16x8*)(Xb + (size_t)(rbase + mg * 16 + lr) * DX + koff);
#pragma unroll
    for (int f = 0; f < 4; ++f)
      b[f] = *(const bf16x8*)(WXT + (size_t)(hb * 64 + f * 16 + lr) * DX + koff);
#pragma unroll
    for (int mg = 0; mg < 2; ++mg)
#pragma unroll
      for (int f = 0; f < 4; ++f)
        acc[mg][f] = __builtin_amdgcn_mfma_f32_16x16x32_bf16(a[mg], b[f], acc[mg][f], 0, 0, 0);
  }
#pragma unroll
  for (int ks = 0; ks < nks; ++ks) {
    const int koff = ks * 32 + lg * 8;
    bf16x8 a[2], b[4];
#pragma unroll
    for (int mg = 0; mg < 2; ++mg)
      a[mg] = *(const bf16x8*)(AG + ((size_t)(rbase + mg * 16 + lr) * 4 + hb) * DX + koff);
#pragma unroll
    for (int f = 0; f < 4; ++f)
      b[f] = *(const bf16x8*)(WNT + (size_t)(hb * 64 + f * 16 + lr) * DX + koff);
#pragma unroll
    for (int mg = 0; mg < 2; ++mg)
#pragma unroll
      for (int f = 0; f < 4; ++f)
        acc[mg][f] = __builtin_amdgcn_mfma_f32_16x16x32_bf16(a[mg], b[f], acc[mg][f], 0, 0, 0);
  }

#pragma unroll
  for (int mg = 0; mg < 2; ++mg)
#pragma unroll
    for (int f = 0; f < 4; ++f)
#pragma unroll
      for (int r = 0; r < 4; ++r) {
        float v = fmaxf(acc[mg][f][r], 0.f);
        size_t idx = (size_t)(rbase + mg * 16 + lg * 4 + r) * 256 + hb * 64 + f * 16 + lr;
        if (OUTB) ((unsigned short*)outv)[idx] = f2b(v);
        else      ((float*)outv)[idx] = v;
      }
}

// ---------------------------------------------------------------------------
extern "C" void kernel_launch(void* const* d_in, const int* in_sizes, int n_in,
                              void* d_out, int out_size, void* d_ws, size_t ws_size,
                              hipStream_t stream) {
  (void)in_sizes; (void)n_in; (void)out_size; (void)ws_size;
  const int*   ids   = (const int*)d_in[0];
  const float* feats = (const float*)d_in[1];
  const int*   adjs  = (const int*)d_in[2];
  const float* Wp    = (const float*)d_in[3];
  const float* Wa1_0 = (const float*)d_in[4];
  const float* wa2_0 = (const float*)d_in[5];
  const float* Wx_0  = (const float*)d_in[6];
  const float* Wn_0  = (const float*)d_in[7];
  const float* Wa1_1 = (const float*)d_in[8];
  const float* wa2_1 = (const float*)d_in[9];
  const float* Wx_1  = (const float*)d_in[10];
  const float* Wn_1  = (const float*)d_in[11];
  float* out = (float*)d_out;

  char* ws = (char*)d_ws;
  size_t off = 0;
  auto alloc = [&](size_t bytes) { char* p = ws + off; off += (bytes + 255) & ~(size_t)255; return p; };
  int*            nodes = (int*)alloc(139776 * 4);
  unsigned short* Pb    = (unsigned short*)alloc((size_t)139776 * 128 * 2);
  float*          T     = (float*)alloc((size_t)8192 * 512 * 4);
  unsigned short* AG    = (unsigned short*)alloc((size_t)8192 * 4 * 256 * 2);
  unsigned short* NF1b  = (unsigned short*)alloc((size_t)8192 * 256 * 2);
  unsigned short* NF0b  = (unsigned short*)alloc((size_t)512 * 256 * 2);
  unsigned short* WB    = (unsigned short*)alloc((size_t)1196032 * 2);

  unsigned short* Wpt  = WB;
  unsigned short* WT0  = WB + 16384;
  unsigned short* WT1  = WB + 278528;
  unsigned short* WXT0 = WB + 802816;
  unsigned short* WNT0 = WB + 868352;
  unsigned short* WXT1 = WB + 933888;
  unsigned short* WNT1 = WB + 1064960;

  transcast_kernel<<<4672, 256, 0, stream>>>(Wp, Wa1_0, Wa1_1, Wx_0, Wn_0,
                                             Wx_1, Wn_1, WB);

  for (int mp = 0; mp < 2; ++mp) {
    const int* adj = adjs + (size_t)mp * 200000 * 32;
    const float* w2_0 = wa2_0 + (size_t)mp * 4 * 128;
    const float* w2_1 = wa2_1 + (size_t)mp * 4 * 128;
    const unsigned short* WT0_top = WT0 + (size_t)mp * 2 * 65536;
    const unsigned short* WT0_bot = WT0 + ((size_t)mp * 2 + 1) * 65536;
    const unsigned short* WT1_top = WT1 + (size_t)mp * 2 * 131072;
    const unsigned short* WT1_bot = WT1 + ((size_t)mp * 2 + 1) * 131072;
    const unsigned short* wxt0 = WXT0 + (size_t)mp * 32768;
    const unsigned short* wnt0 = WNT0 + (size_t)mp * 32768;
    const unsigned short* wxt1 = WXT1 + (size_t)mp * 65536;
    const unsigned short* wnt1 = WNT1 + (size_t)mp * 65536;

    unsigned key0[2], key1[2];
    for (int li = 0; li < 2; ++li) {
      unsigned K0, K1;
      tf2x32(0u, 42u, 0u, (unsigned)(mp * 16 + li), K0, K1);
      tf2x32(K0, K1, 0u, 1u, key0[li], key1[li]);
    }

    hipMemcpyAsync(nodes, ids, 512 * sizeof(int), hipMemcpyDeviceToDevice, stream);
    frontier_kernel<<<32, 256, 0, stream>>>(adj, ids, nodes + 512, 8192, key0[0], key1[0]);
    frontier_kernel<<<512, 256, 0, stream>>>(adj, nodes + 512, nodes + 8704, 131072, key0[1], key1[1]);

    mfma_gemm<0, true><<<dim3(1092, 1), 256, 0, stream>>>(
        feats, nodes, Wpt, Pb, 128, 128);

    const unsigned short* Pb0 = Pb;
    const unsigned short* Pb1 = Pb + (size_t)512 * 128;
    const unsigned short* Pb2 = Pb + (size_t)8704 * 128;

    // ---- L0 agg B: x=Pb1 (8192), nb=Pb2 (131072) -> NF1b
    mfma_gemm<1, false><<<dim3(64, 4), 256, 0, stream>>>(
        Pb1, nullptr, WT0_top, T, 128, 512);
    aggsc_mfma<<<4096, 256, 0, stream>>>(Pb2, T, WT0_bot, w2_0, AG, 128);
    outg_kernel<128, true><<<dim3(64, 4), 256, 0, stream>>>(
        Pb1, AG, wxt0, wnt0, NF1b);

    // ---- L0 agg A: x=Pb0 (512), nb=Pb1 (8192) -> NF0b
    mfma_gemm<1, false><<<dim3(4, 4), 256, 0, stream>>>(
        Pb0, nullptr, WT0_top, T, 128, 512);
    aggsc_mfma<<<256, 256, 0, stream>>>(Pb1, T, WT0_bot, w2_0, AG, 128);
    outg_kernel<128, true><<<dim3(4, 4), 256, 0, stream>>>(
        Pb0, AG, wxt0, wnt0, NF0b);

    // ---- L1: x=NF0b (512), nb=NF1b (8192) -> d_out[mp] fp32
    mfma_gemm<1, false><<<dim3(4, 4), 256, 0, stream>>>(
        NF0b, nullptr, WT1_top, T, 256, 512);
    aggsc_mfma<<<256, 256, 0, stream>>>(NF1b, T, WT1_bot, w2_1, AG, 256);
    outg_kernel<256, false><<<dim3(4, 4), 256, 0, stream>>>(
        NF0b, AG, wxt1, wnt1, out + (size_t)mp * 512 * 256);
  }
}

// Round 7
// 409.182 us; speedup vs baseline: 3.3063x; 1.0200x over previous
//
#include <hip/hip_runtime.h>
#include <math.h>

// ---------------------------------------------------------------------------
// GraphSAGE-attention forward (round 7: compile-time K -> full unroll of the
// MFMA K-loops (batch global loads, hide L2 latency); fused 2-hop frontier).
// RNG verified R3: partitionable threefry, bits = o0^o1, split child (0,1).
// C/D layout (m89): col = lane&15, row = (lane>>4)*4 + reg.
// A/B frag: lane l holds 8 contiguous k at row/col = l&15, k0 = (l>>4)*8.
// ---------------------------------------------------------------------------

typedef __attribute__((ext_vector_type(8))) short bf16x8;
typedef __attribute__((ext_vector_type(4))) float f32x4;

__device__ __forceinline__ float b2f(unsigned short u) {
  union { unsigned u; float f; } c; c.u = ((unsigned)u) << 16; return c.f;
}
__device__ __forceinline__ unsigned short f2b(float f) {
  union { float f; unsigned u; } c; c.f = f;
  return (unsigned short)((c.u + 0x7FFFu + ((c.u >> 16) & 1u)) >> 16);
}

// tanh(x) = 1 - 2/(1+e^{2x}) via v_exp_f32 + v_rcp_f32 (saturates correctly).
__device__ __forceinline__ float fast_tanh(float x) {
  float y = x * 2.8853900817779268f;   // 2*log2(e)
  float z; asm("v_exp_f32 %0, %1" : "=v"(z) : "v"(y));
  float zp1 = z + 1.f;
  float w; asm("v_rcp_f32 %0, %1" : "=v"(w) : "v"(zp1));
  return fmaf(-2.f, w, 1.f);
}
// exp(x) (softmax: shift-invariant, monotone -> safe)
__device__ __forceinline__ float fast_exp(float x) {
  float y = x * 1.4426950408889634f;
  float z; asm("v_exp_f32 %0, %1" : "=v"(z) : "v"(y));
  return z;
}

__host__ __device__ __forceinline__ void tf2x32(unsigned k0, unsigned k1,
                                                unsigned x0, unsigned x1,
                                                unsigned& o0, unsigned& o1) {
  const unsigned ks2 = k0 ^ k1 ^ 0x1BD11BDAu;
  unsigned v0 = x0 + k0, v1 = x1 + k1;
#define TFR(r) { v0 += v1; v1 = (v1 << (r)) | (v1 >> (32 - (r))); v1 ^= v0; }
  TFR(13) TFR(15) TFR(26) TFR(6)
  v0 += k1;  v1 += ks2 + 1u;
  TFR(17) TFR(29) TFR(16) TFR(24)
  v0 += ks2; v1 += k0 + 2u;
  TFR(13) TFR(15) TFR(26) TFR(6)
  v0 += k0;  v1 += k1 + 3u;
  TFR(17) TFR(29) TFR(16) TFR(24)
  v0 += k1;  v1 += ks2 + 4u;
  TFR(13) TFR(15) TFR(26) TFR(6)
  v0 += ks2; v1 += k0 + 5u;
#undef TFR
  o0 = v0; o1 = v1;
}

// Fused 2-hop frontier: thread i in [0,131072) recomputes hop-1 for its
// parent group (L1-broadcast), writes frontier2; lane (i&15)==0 writes
// frontier1; i<512 copies ids. Replaces memcpy + 2 kernels.
__global__ void frontier2_kernel(const int* __restrict__ adj,
                                 const int* __restrict__ ids,
                                 int* __restrict__ nodes,
                                 unsigned k0a, unsigned k1a,
                                 unsigned k0b, unsigned k1b) {
  int i = blockIdx.x * 256 + threadIdx.x;
  int j = i >> 4;
  unsigned y0, y1;
  tf2x32(k0a, k1a, 0u, (unsigned)j, y0, y1);
  int col1 = (int)((y0 ^ y1) & 31u);
  int p0 = ids[j >> 4];
  int f1 = adj[(size_t)p0 * 32 + col1];
  tf2x32(k0b, k1b, 0u, (unsigned)i, y0, y1);
  int col2 = (int)((y0 ^ y1) & 31u);
  int f2 = adj[(size_t)f1 * 32 + col2];
  nodes[8704 + i] = f2;
  if ((i & 15) == 0) nodes[512 + j] = f1;
  if (i < 512) nodes[i] = ids[i];
}

// ---------------------------------------------------------------------------
// transcast: bf16 transposed weights, linear ranges (see R5 comment).
// ---------------------------------------------------------------------------
__global__ void transcast_kernel(const float* __restrict__ Wp,
                                 const float* __restrict__ Wa1_0,
                                 const float* __restrict__ Wa1_1,
                                 const float* __restrict__ Wx_0,
                                 const float* __restrict__ Wn_0,
                                 const float* __restrict__ Wx_1,
                                 const float* __restrict__ Wn_1,
                                 unsigned short* __restrict__ Wpt) {
  int o = blockIdx.x * 256 + threadIdx.x;
  if (o >= 1196032) return;
  float v;
  if (o < 16384) {
    int k = o & 127, c = o >> 7;
    v = Wp[k * 128 + c];
  } else if (o < 278528) {
    int o2 = o - 16384;
    int k = o2 & 127, c = (o2 >> 7) & 127, h = (o2 >> 14) & 3,
        half = (o2 >> 16) & 1, mpi = o2 >> 17;
    v = Wa1_0[(((size_t)(mpi * 4 + h) * 256) + half * 128 + k) * 128 + c];
  } else if (o < 802816) {
    int o3 = o - 278528;
    int k = o3 & 255, c = (o3 >> 8) & 127, h = (o3 >> 15) & 3,
        half = (o3 >> 17) & 1, mpi = o3 >> 18;
    v = Wa1_1[(((size_t)(mpi * 4 + h) * 512) + half * 256 + k) * 128 + c];
  } else if (o < 868352) {
    int o4 = o - 802816;
    int k = o4 & 127, oo = (o4 >> 7) & 63, h = (o4 >> 13) & 3, mpi = o4 >> 15;
    v = Wx_0[(((size_t)(mpi * 4 + h) * 128) + k) * 64 + oo];
  } else if (o < 933888) {
    int o4 = o - 868352;
    int k = o4 & 127, oo = (o4 >> 7) & 63, h = (o4 >> 13) & 3, mpi = o4 >> 15;
    v = Wn_0[(((size_t)(mpi * 4 + h) * 128) + k) * 64 + oo];
  } else if (o < 1064960) {
    int o5 = o - 933888;
    int k = o5 & 255, oo = (o5 >> 8) & 63, h = (o5 >> 14) & 3, mpi = o5 >> 16;
    v = Wx_1[(((size_t)(mpi * 4 + h) * 256) + k) * 64 + oo];
  } else {
    int o5 = o - 1064960;
    int k = o5 & 255, oo = (o5 >> 8) & 63, h = (o5 >> 14) & 3, mpi = o5 >> 16;
    v = Wn_1[(((size_t)(mpi * 4 + h) * 256) + k) * 64 + oo];
  }
  Wpt[o] = f2b(v);
}

// ---------------------------------------------------------------------------
// MFMA GEMM (prep / T): block = 128 rows x 128 cols, 4 waves x 32 rows.
// K = NKS*32 compile-time -> fully unrolled, loads batched.
// MODE 0: bf16 C [M][ldc] (prep: A fp32 + gather)   MODE 1: f32 C, col hb*128
// ---------------------------------------------------------------------------
template <int MODE, bool A_F32, int NKS>
__global__ __launch_bounds__(256) void mfma_gemm(
    const void* __restrict__ Av, const int* __restrict__ gather,
    const unsigned short* __restrict__ WT, void* __restrict__ Cv,
    int ldc) {
  constexpr int K = NKS * 32;
  const int t = threadIdx.x;
  const int w = t >> 6, l = t & 63;
  const int lr = l & 15, lg = l >> 4;
  const int hb = blockIdx.y;
  const int rbase = blockIdx.x * 128 + w * 32;

  const unsigned short* Wb = WT + (size_t)hb * 128 * K;
  f32x4 acc[2][8] = {};

  int arow[2];
#pragma unroll
  for (int mg = 0; mg < 2; ++mg) {
    int row = rbase + mg * 16 + lr;
    arow[mg] = gather ? gather[row] : row;
  }
  const float* Af = (const float*)Av;
  const unsigned short* Ab = (const unsigned short*)Av;

#pragma unroll
  for (int ks = 0; ks < NKS; ++ks) {
    const int koff = ks * 32 + lg * 8;
    bf16x8 a[2], b[8];
#pragma unroll
    for (int mg = 0; mg < 2; ++mg) {
      if (A_F32) {
        const float* p = Af + (size_t)arow[mg] * K + koff;
        float4 v0 = *(const float4*)p;
        float4 v1 = *(const float4*)(p + 4);
        union { short s[8]; bf16x8 v; } u;
        u.s[0] = (short)f2b(v0.x); u.s[1] = (short)f2b(v0.y);
        u.s[2] = (short)f2b(v0.z); u.s[3] = (short)f2b(v0.w);
        u.s[4] = (short)f2b(v1.x); u.s[5] = (short)f2b(v1.y);
        u.s[6] = (short)f2b(v1.z); u.s[7] = (short)f2b(v1.w);
        a[mg] = u.v;
      } else {
        a[mg] = *(const bf16x8*)(Ab + (size_t)arow[mg] * K + koff);
      }
    }
#pragma unroll
    for (int f = 0; f < 8; ++f)
      b[f] = *(const bf16x8*)(Wb + (size_t)(f * 16 + lr) * K + koff);
#pragma unroll
    for (int mg = 0; mg < 2; ++mg)
#pragma unroll
      for (int f = 0; f < 8; ++f)
        acc[mg][f] = __builtin_amdgcn_mfma_f32_16x16x32_bf16(a[mg], b[f], acc[mg][f], 0, 0, 0);
  }

  if (MODE == 0) {
    unsigned short* Cb = (unsigned short*)Cv;
#pragma unroll
    for (int mg = 0; mg < 2; ++mg)
#pragma unroll
      for (int f = 0; f < 8; ++f)
#pragma unroll
        for (int r = 0; r < 4; ++r)
          Cb[(size_t)(rbase + mg * 16 + lg * 4 + r) * ldc + f * 16 + lr] =
              f2b(acc[mg][f][r]);
  } else {
    float* Cf = (float*)Cv;
#pragma unroll
    for (int mg = 0; mg < 2; ++mg)
#pragma unroll
      for (int f = 0; f < 8; ++f)
#pragma unroll
        for (int r = 0; r < 4; ++r)
          Cf[(size_t)(rbase + mg * 16 + lg * 4 + r) * ldc + hb * 128 + f * 16 + lr] =
              acc[mg][f][r];
  }
}

// ---------------------------------------------------------------------------
// AGGSC+AGG fused: block = 32 NB rows (2 m-rows x 16 samples), 4 waves=heads.
// K compile-time -> unrolled. U = nb@Wa1_bot (MFMA); score/softmax; AG.
// ---------------------------------------------------------------------------
template <int NKS>
__global__ __launch_bounds__(256) void aggsc_mfma(
    const unsigned short* __restrict__ NB,   // [m*16][K] bf16
    const float* __restrict__ Tb,            // [m][512]
    const unsigned short* __restrict__ WTbot,// [4][128][K] bf16
    const float* __restrict__ wa2,           // [4][128]
    unsigned short* __restrict__ AG) {       // [m][4][K] bf16
  constexpr int K = NKS * 32;
  const int t = threadIdx.x;
  const int hb = t >> 6, l = t & 63;
  const int lr = l & 15, lg = l >> 4;
  const int rbase = blockIdx.x * 32;

  __shared__ float alsh[4][2][16];

  const unsigned short* Wb = WTbot + (size_t)hb * 128 * K;
  f32x4 acc[2][8] = {};

#pragma unroll
  for (int ks = 0; ks < NKS; ++ks) {
    const int koff = ks * 32 + lg * 8;
    bf16x8 a[2], b[8];
#pragma unroll
    for (int mg = 0; mg < 2; ++mg)
      a[mg] = *(const bf16x8*)(NB + (size_t)(rbase + mg * 16 + lr) * K + koff);
#pragma unroll
    for (int f = 0; f < 8; ++f)
      b[f] = *(const bf16x8*)(Wb + (size_t)(f * 16 + lr) * K + koff);
#pragma unroll
    for (int mg = 0; mg < 2; ++mg)
#pragma unroll
      for (int f = 0; f < 8; ++f)
        acc[mg][f] = __builtin_amdgcn_mfma_f32_16x16x32_bf16(a[mg], b[f], acc[mg][f], 0, 0, 0);
  }

  float w2[8];
#pragma unroll
  for (int f = 0; f < 8; ++f) w2[f] = wa2[hb * 128 + f * 16 + lr];
#pragma unroll
  for (int mg = 0; mg < 2; ++mg) {
    const int i = blockIdx.x * 2 + mg;
    float tv[8];
#pragma unroll
    for (int f = 0; f < 8; ++f)
      tv[f] = Tb[(size_t)i * 512 + hb * 128 + f * 16 + lr];
    float sc[4];
#pragma unroll
    for (int r = 0; r < 4; ++r) {
      float s = 0.f;
#pragma unroll
      for (int f = 0; f < 8; ++f)
        s += fast_tanh(acc[mg][f][r] + tv[f]) * w2[f];
      s += __shfl_xor(s, 1); s += __shfl_xor(s, 2);
      s += __shfl_xor(s, 4); s += __shfl_xor(s, 8);
      sc[r] = s;
    }
    float mx = fmaxf(fmaxf(sc[0], sc[1]), fmaxf(sc[2], sc[3]));
    mx = fmaxf(mx, __shfl_xor(mx, 16));
    mx = fmaxf(mx, __shfl_xor(mx, 32));
    float e0 = fast_exp(sc[0] - mx), e1 = fast_exp(sc[1] - mx);
    float e2 = fast_exp(sc[2] - mx), e3 = fast_exp(sc[3] - mx);
    float sum = e0 + e1 + e2 + e3;
    sum += __shfl_xor(sum, 16); sum += __shfl_xor(sum, 32);
    float inv = 1.f / sum;
    if (lr == 0) {
      alsh[hb][mg][lg * 4 + 0] = e0 * inv;
      alsh[hb][mg][lg * 4 + 1] = e1 * inv;
      alsh[hb][mg][lg * 4 + 2] = e2 * inv;
      alsh[hb][mg][lg * 4 + 3] = e3 * inv;
    }
  }
  __syncthreads();

  // AG phase: wave hb computes AG[i][hb][:] for its 2 m-rows.
  constexpr int NCH = K >> 7;   // 1 (K=128) or 2 (K=256)
#pragma unroll
  for (int mg = 0; mg < 2; ++mg) {
    const int i = blockIdx.x * 2 + mg;
    float al[16];
#pragma unroll
    for (int s = 0; s < 16; ++s) al[s] = alsh[hb][mg][s];
#pragma unroll
    for (int c = 0; c < NCH; ++c) {
      const int d = l * 2 + c * 128;
      const unsigned short* nbp = NB + (size_t)(rbase + mg * 16) * K + d;
      float a0 = 0.f, a1 = 0.f;
#pragma unroll
      for (int s = 0; s < 16; ++s) {
        unsigned v = *(const unsigned*)(nbp + (size_t)s * K);
        a0 = fmaf(al[s], b2f((unsigned short)(v & 0xffffu)), a0);
        a1 = fmaf(al[s], b2f((unsigned short)(v >> 16)), a1);
      }
      unsigned o = (unsigned)f2b(a0) | ((unsigned)f2b(a1) << 16);
      *(unsigned*)(AG + ((size_t)i * 4 + hb) * K + d) = o;
    }
  }
}

// ---------------------------------------------------------------------------
// OUTG: out[m, hb*64+c] = relu( x @ Wx[hb] + agg[hb] @ Wn[hb] )  (MFMA)
// ---------------------------------------------------------------------------
template <int DX, bool OUTB>
__global__ __launch_bounds__(256) void outg_kernel(
    const unsigned short* __restrict__ Xb,   // [M][DX]
    const unsigned short* __restrict__ AG,   // [M][4][DX]
    const unsigned short* __restrict__ WXT,  // [4][64][DX]
    const unsigned short* __restrict__ WNT,  // [4][64][DX]
    void* __restrict__ outv) {               // [M][256]
  const int t = threadIdx.x;
  const int w = t >> 6, l = t & 63;
  const int lr = l & 15, lg = l >> 4;
  const int hb = blockIdx.y;
  const int rbase = blockIdx.x * 128 + w * 32;
  f32x4 acc[2][4] = {};
  constexpr int nks = DX >> 5;

#pragma unroll
  for (int ks = 0; ks < nks; ++ks) {
    const int koff = ks * 32 + lg * 8;
    bf16x8 a[2], b[4];
#pragma unroll
    for (int mg = 0; mg < 2; ++mg)
      a[mg] = *(const bf16x8*)(Xb + (size_t)(rbase + mg * 16 + lr) * DX + koff);
#pragma unroll
    for (int f = 0; f < 4; ++f)
      b[f] = *(const bf16x8*)(WXT + (size_t)(hb * 64 + f * 16 + lr) * DX + koff);
#pragma unroll
    for (int mg = 0; mg < 2; ++mg)
#pragma unroll
      for (int f = 0; f < 4; ++f)
        acc[mg][f] = __builtin_amdgcn_mfma_f32_16x16x32_bf16(a[mg], b[f], acc[mg][f], 0, 0, 0);
  }
#pragma unroll
  for (int ks = 0; ks < nks; ++ks) {
    const int koff = ks * 32 + lg * 8;
    bf16x8 a[2], b[4];
#pragma unroll
    for (int mg = 0; mg < 2; ++mg)
      a[mg] = *(const bf16x8*)(AG + ((size_t)(rbase + mg * 16 + lr) * 4 + hb) * DX + koff);
#pragma unroll
    for (int f = 0; f < 4; ++f)
      b[f] = *(const bf16x8*)(WNT + (size_t)(hb * 64 + f * 16 + lr) * DX + koff);
#pragma unroll
    for (int mg = 0; mg < 2; ++mg)
#pragma unroll
      for (int f = 0; f < 4; ++f)
        acc[mg][f] = __builtin_amdgcn_mfma_f32_16x16x32_bf16(a[mg], b[f], acc[mg][f], 0, 0, 0);
  }

#pragma unroll
  for (int mg = 0; mg < 2; ++mg)
#pragma unroll
    for (int f = 0; f < 4; ++f)
#pragma unroll
      for (int r = 0; r < 4; ++r) {
        float v = fmaxf(acc[mg][f][r], 0.f);
        size_t idx = (size_t)(rbase + mg * 16 + lg * 4 + r) * 256 + hb * 64 + f * 16 + lr;
        if (OUTB) ((unsigned short*)outv)[idx] = f2b(v);
        else      ((float*)outv)[idx] = v;
      }
}

// ---------------------------------------------------------------------------
extern "C" void kernel_launch(void* const* d_in, const int* in_sizes, int n_in,
                              void* d_out, int out_size, void* d_ws, size_t ws_size,
                              hipStream_t stream) {
  (void)in_sizes; (void)n_in; (void)out_size; (void)ws_size;
  const int*   ids   = (const int*)d_in[0];
  const float* feats = (const float*)d_in[1];
  const int*   adjs  = (const int*)d_in[2];
  const float* Wp    = (const float*)d_in[3];
  const float* Wa1_0 = (const float*)d_in[4];
  const float* wa2_0 = (const float*)d_in[5];
  const float* Wx_0  = (const float*)d_in[6];
  const float* Wn_0  = (const float*)d_in[7];
  const float* Wa1_1 = (const float*)d_in[8];
  const float* wa2_1 = (const float*)d_in[9];
  const float* Wx_1  = (const float*)d_in[10];
  const float* Wn_1  = (const float*)d_in[11];
  float* out = (float*)d_out;

  char* ws = (char*)d_ws;
  size_t off = 0;
  auto alloc = [&](size_t bytes) { char* p = ws + off; off += (bytes + 255) & ~(size_t)255; return p; };
  int*            nodes = (int*)alloc(139776 * 4);
  unsigned short* Pb    = (unsigned short*)alloc((size_t)139776 * 128 * 2);
  float*          T     = (float*)alloc((size_t)8192 * 512 * 4);
  unsigned short* AG    = (unsigned short*)alloc((size_t)8192 * 4 * 256 * 2);
  unsigned short* NF1b  = (unsigned short*)alloc((size_t)8192 * 256 * 2);
  unsigned short* NF0b  = (unsigned short*)alloc((size_t)512 * 256 * 2);
  unsigned short* WB    = (unsigned short*)alloc((size_t)1196032 * 2);

  unsigned short* Wpt  = WB;
  unsigned short* WT0  = WB + 16384;
  unsigned short* WT1  = WB + 278528;
  unsigned short* WXT0 = WB + 802816;
  unsigned short* WNT0 = WB + 868352;
  unsigned short* WXT1 = WB + 933888;
  unsigned short* WNT1 = WB + 1064960;

  transcast_kernel<<<4672, 256, 0, stream>>>(Wp, Wa1_0, Wa1_1, Wx_0, Wn_0,
                                             Wx_1, Wn_1, WB);

  for (int mp = 0; mp < 2; ++mp) {
    const int* adj = adjs + (size_t)mp * 200000 * 32;
    const float* w2_0 = wa2_0 + (size_t)mp * 4 * 128;
    const float* w2_1 = wa2_1 + (size_t)mp * 4 * 128;
    const unsigned short* WT0_top = WT0 + (size_t)mp * 2 * 65536;
    const unsigned short* WT0_bot = WT0 + ((size_t)mp * 2 + 1) * 65536;
    const unsigned short* WT1_top = WT1 + (size_t)mp * 2 * 131072;
    const unsigned short* WT1_bot = WT1 + ((size_t)mp * 2 + 1) * 131072;
    const unsigned short* wxt0 = WXT0 + (size_t)mp * 32768;
    const unsigned short* wnt0 = WNT0 + (size_t)mp * 32768;
    const unsigned short* wxt1 = WXT1 + (size_t)mp * 65536;
    const unsigned short* wnt1 = WNT1 + (size_t)mp * 65536;

    unsigned key0[2], key1[2];
    for (int li = 0; li < 2; ++li) {
      unsigned K0, K1;
      tf2x32(0u, 42u, 0u, (unsigned)(mp * 16 + li), K0, K1);
      tf2x32(K0, K1, 0u, 1u, key0[li], key1[li]);
    }

    frontier2_kernel<<<512, 256, 0, stream>>>(adj, ids, nodes,
                                              key0[0], key1[0], key0[1], key1[1]);

    mfma_gemm<0, true, 4><<<dim3(1092, 1), 256, 0, stream>>>(
        feats, nodes, Wpt, Pb, 128);

    const unsigned short* Pb0 = Pb;
    const unsigned short* Pb1 = Pb + (size_t)512 * 128;
    const unsigned short* Pb2 = Pb + (size_t)8704 * 128;

    // ---- L0 agg B: x=Pb1 (8192), nb=Pb2 (131072) -> NF1b
    mfma_gemm<1, false, 4><<<dim3(64, 4), 256, 0, stream>>>(
        Pb1, nullptr, WT0_top, T, 512);
    aggsc_mfma<4><<<4096, 256, 0, stream>>>(Pb2, T, WT0_bot, w2_0, AG);
    outg_kernel<128, true><<<dim3(64, 4), 256, 0, stream>>>(
        Pb1, AG, wxt0, wnt0, NF1b);

    // ---- L0 agg A: x=Pb0 (512), nb=Pb1 (8192) -> NF0b
    mfma_gemm<1, false, 4><<<dim3(4, 4), 256, 0, stream>>>(
        Pb0, nullptr, WT0_top, T, 512);
    aggsc_mfma<4><<<256, 256, 0, stream>>>(Pb1, T, WT0_bot, w2_0, AG);
    outg_kernel<128, true><<<dim3(4, 4), 256, 0, stream>>>(
        Pb0, AG, wxt0, wnt0, NF0b);

    // ---- L1: x=NF0b (512), nb=NF1b (8192) -> d_out[mp] fp32
    mfma_gemm<1, false, 8><<<dim3(4, 4), 256, 0, stream>>>(
        NF0b, nullptr, WT1_top, T, 512);
    aggsc_mfma<8><<<256, 256, 0, stream>>>(NF1b, T, WT1_bot, w2_1, AG);
    outg_kernel<256, false><<<dim3(4, 4), 256, 0, stream>>>(
        NF0b, AG, wxt1, wnt1, out + (size_t)mp * 512 * 256);
  }
}

// Round 8
// 406.770 us; speedup vs baseline: 3.3259x; 1.0059x over previous
//
#include <hip/hip_runtime.h>
#include <math.h>

// ---------------------------------------------------------------------------
// GraphSAGE-attention forward (round 8: aggsc re-tiled to 256 rows/block x
// one head/block -- 8x less weight traffic, L1-resident weights, 4-row-group
// waves for 32:12 MFMA:load ratio; wave-local epilogue, no barrier).
// RNG verified R3. C/D layout (m89): col=lane&15, row=(lane>>4)*4+reg.
// ---------------------------------------------------------------------------

typedef __attribute__((ext_vector_type(8))) short bf16x8;
typedef __attribute__((ext_vector_type(4))) float f32x4;

__device__ __forceinline__ float b2f(unsigned short u) {
  union { unsigned u; float f; } c; c.u = ((unsigned)u) << 16; return c.f;
}
__device__ __forceinline__ unsigned short f2b(float f) {
  union { float f; unsigned u; } c; c.f = f;
  return (unsigned short)((c.u + 0x7FFFu + ((c.u >> 16) & 1u)) >> 16);
}

__device__ __forceinline__ float fast_tanh(float x) {
  float y = x * 2.8853900817779268f;   // 2*log2(e)
  float z; asm("v_exp_f32 %0, %1" : "=v"(z) : "v"(y));
  float zp1 = z + 1.f;
  float w; asm("v_rcp_f32 %0, %1" : "=v"(w) : "v"(zp1));
  return fmaf(-2.f, w, 1.f);
}
__device__ __forceinline__ float fast_exp(float x) {
  float y = x * 1.4426950408889634f;
  float z; asm("v_exp_f32 %0, %1" : "=v"(z) : "v"(y));
  return z;
}

__host__ __device__ __forceinline__ void tf2x32(unsigned k0, unsigned k1,
                                                unsigned x0, unsigned x1,
                                                unsigned& o0, unsigned& o1) {
  const unsigned ks2 = k0 ^ k1 ^ 0x1BD11BDAu;
  unsigned v0 = x0 + k0, v1 = x1 + k1;
#define TFR(r) { v0 += v1; v1 = (v1 << (r)) | (v1 >> (32 - (r))); v1 ^= v0; }
  TFR(13) TFR(15) TFR(26) TFR(6)
  v0 += k1;  v1 += ks2 + 1u;
  TFR(17) TFR(29) TFR(16) TFR(24)
  v0 += ks2; v1 += k0 + 2u;
  TFR(13) TFR(15) TFR(26) TFR(6)
  v0 += k0;  v1 += k1 + 3u;
  TFR(17) TFR(29) TFR(16) TFR(24)
  v0 += k1;  v1 += ks2 + 4u;
  TFR(13) TFR(15) TFR(26) TFR(6)
  v0 += ks2; v1 += k0 + 5u;
#undef TFR
  o0 = v0; o1 = v1;
}

__global__ void frontier2_kernel(const int* __restrict__ adj,
                                 const int* __restrict__ ids,
                                 int* __restrict__ nodes,
                                 unsigned k0a, unsigned k1a,
                                 unsigned k0b, unsigned k1b) {
  int i = blockIdx.x * 256 + threadIdx.x;
  int j = i >> 4;
  unsigned y0, y1;
  tf2x32(k0a, k1a, 0u, (unsigned)j, y0, y1);
  int col1 = (int)((y0 ^ y1) & 31u);
  int p0 = ids[j >> 4];
  int f1 = adj[(size_t)p0 * 32 + col1];
  tf2x32(k0b, k1b, 0u, (unsigned)i, y0, y1);
  int col2 = (int)((y0 ^ y1) & 31u);
  int f2 = adj[(size_t)f1 * 32 + col2];
  nodes[8704 + i] = f2;
  if ((i & 15) == 0) nodes[512 + j] = f1;
  if (i < 512) nodes[i] = ids[i];
}

// ---------------------------------------------------------------------------
// transcast: bf16 transposed weights, linear ranges (see R5 comment).
// ---------------------------------------------------------------------------
__global__ void transcast_kernel(const float* __restrict__ Wp,
                                 const float* __restrict__ Wa1_0,
                                 const float* __restrict__ Wa1_1,
                                 const float* __restrict__ Wx_0,
                                 const float* __restrict__ Wn_0,
                                 const float* __restrict__ Wx_1,
                                 const float* __restrict__ Wn_1,
                                 unsigned short* __restrict__ Wpt) {
  int o = blockIdx.x * 256 + threadIdx.x;
  if (o >= 1196032) return;
  float v;
  if (o < 16384) {
    int k = o & 127, c = o >> 7;
    v = Wp[k * 128 + c];
  } else if (o < 278528) {
    int o2 = o - 16384;
    int k = o2 & 127, c = (o2 >> 7) & 127, h = (o2 >> 14) & 3,
        half = (o2 >> 16) & 1, mpi = o2 >> 17;
    v = Wa1_0[(((size_t)(mpi * 4 + h) * 256) + half * 128 + k) * 128 + c];
  } else if (o < 802816) {
    int o3 = o - 278528;
    int k = o3 & 255, c = (o3 >> 8) & 127, h = (o3 >> 15) & 3,
        half = (o3 >> 17) & 1, mpi = o3 >> 18;
    v = Wa1_1[(((size_t)(mpi * 4 + h) * 512) + half * 256 + k) * 128 + c];
  } else if (o < 868352) {
    int o4 = o - 802816;
    int k = o4 & 127, oo = (o4 >> 7) & 63, h = (o4 >> 13) & 3, mpi = o4 >> 15;
    v = Wx_0[(((size_t)(mpi * 4 + h) * 128) + k) * 64 + oo];
  } else if (o < 933888) {
    int o4 = o - 868352;
    int k = o4 & 127, oo = (o4 >> 7) & 63, h = (o4 >> 13) & 3, mpi = o4 >> 15;
    v = Wn_0[(((size_t)(mpi * 4 + h) * 128) + k) * 64 + oo];
  } else if (o < 1064960) {
    int o5 = o - 933888;
    int k = o5 & 255, oo = (o5 >> 8) & 63, h = (o5 >> 14) & 3, mpi = o5 >> 16;
    v = Wx_1[(((size_t)(mpi * 4 + h) * 256) + k) * 64 + oo];
  } else {
    int o5 = o - 1064960;
    int k = o5 & 255, oo = (o5 >> 8) & 63, h = (o5 >> 14) & 3, mpi = o5 >> 16;
    v = Wn_1[(((size_t)(mpi * 4 + h) * 256) + k) * 64 + oo];
  }
  Wpt[o] = f2b(v);
}

// ---------------------------------------------------------------------------
// MFMA GEMM (prep / T): block = 128 rows x 128 cols, 4 waves x 32 rows.
// ---------------------------------------------------------------------------
template <int MODE, bool A_F32, int NKS>
__global__ __launch_bounds__(256) void mfma_gemm(
    const void* __restrict__ Av, const int* __restrict__ gather,
    const unsigned short* __restrict__ WT, void* __restrict__ Cv,
    int ldc) {
  constexpr int K = NKS * 32;
  const int t = threadIdx.x;
  const int w = t >> 6, l = t & 63;
  const int lr = l & 15, lg = l >> 4;
  const int hb = blockIdx.y;
  const int rbase = blockIdx.x * 128 + w * 32;

  const unsigned short* Wb = WT + (size_t)hb * 128 * K;
  f32x4 acc[2][8] = {};

  int arow[2];
#pragma unroll
  for (int mg = 0; mg < 2; ++mg) {
    int row = rbase + mg * 16 + lr;
    arow[mg] = gather ? gather[row] : row;
  }
  const float* Af = (const float*)Av;
  const unsigned short* Ab = (const unsigned short*)Av;

#pragma unroll
  for (int ks = 0; ks < NKS; ++ks) {
    const int koff = ks * 32 + lg * 8;
    bf16x8 a[2], b[8];
#pragma unroll
    for (int mg = 0; mg < 2; ++mg) {
      if (A_F32) {
        const float* p = Af + (size_t)arow[mg] * K + koff;
        float4 v0 = *(const float4*)p;
        float4 v1 = *(const float4*)(p + 4);
        union { short s[8]; bf16x8 v; } u;
        u.s[0] = (short)f2b(v0.x); u.s[1] = (short)f2b(v0.y);
        u.s[2] = (short)f2b(v0.z); u.s[3] = (short)f2b(v0.w);
        u.s[4] = (short)f2b(v1.x); u.s[5] = (short)f2b(v1.y);
        u.s[6] = (short)f2b(v1.z); u.s[7] = (short)f2b(v1.w);
        a[mg] = u.v;
      } else {
        a[mg] = *(const bf16x8*)(Ab + (size_t)arow[mg] * K + koff);
      }
    }
#pragma unroll
    for (int f = 0; f < 8; ++f)
      b[f] = *(const bf16x8*)(Wb + (size_t)(f * 16 + lr) * K + koff);
#pragma unroll
    for (int mg = 0; mg < 2; ++mg)
#pragma unroll
      for (int f = 0; f < 8; ++f)
        acc[mg][f] = __builtin_amdgcn_mfma_f32_16x16x32_bf16(a[mg], b[f], acc[mg][f], 0, 0, 0);
  }

  if (MODE == 0) {
    unsigned short* Cb = (unsigned short*)Cv;
#pragma unroll
    for (int mg = 0; mg < 2; ++mg)
#pragma unroll
      for (int f = 0; f < 8; ++f)
#pragma unroll
        for (int r = 0; r < 4; ++r)
          Cb[(size_t)(rbase + mg * 16 + lg * 4 + r) * ldc + f * 16 + lr] =
              f2b(acc[mg][f][r]);
  } else {
    float* Cf = (float*)Cv;
#pragma unroll
    for (int mg = 0; mg < 2; ++mg)
#pragma unroll
      for (int f = 0; f < 8; ++f)
#pragma unroll
        for (int r = 0; r < 4; ++r)
          Cf[(size_t)(rbase + mg * 16 + lg * 4 + r) * ldc + hb * 128 + f * 16 + lr] =
              acc[mg][f][r];
  }
}

// ---------------------------------------------------------------------------
// AGGSC+AGG fused, re-tiled: grid = (M/256, 4 heads); block = 4 waves;
// wave = 64 NB rows (4 mg) = 4 m-rows, ONE head (blockIdx.y) per block.
// Per-block weight footprint 32KB (L1-resident, shared by all 4 waves).
// Epilogue wave-local: alpha via per-wave LDS region, no __syncthreads.
// ---------------------------------------------------------------------------
template <int NKS>
__global__ __launch_bounds__(256, 2) void aggsc_mfma(
    const unsigned short* __restrict__ NB,   // [M][K] bf16
    const float* __restrict__ Tb,            // [m][512]
    const unsigned short* __restrict__ WTbot,// [4][128][K] bf16
    const float* __restrict__ wa2,           // [4][128]
    unsigned short* __restrict__ AG) {       // [m][4][K] bf16
  constexpr int K = NKS * 32;
  const int t = threadIdx.x;
  const int w = t >> 6, l = t & 63;
  const int lr = l & 15, lg = l >> 4;
  const int hb = blockIdx.y;
  const int rbase = blockIdx.x * 256 + w * 64;

  __shared__ float alsh[4][4][16];   // [wave][mg][sample]

  const unsigned short* Wb = WTbot + (size_t)hb * 128 * K;
  f32x4 acc[4][8] = {};

#pragma unroll
  for (int ks = 0; ks < NKS; ++ks) {
    const int koff = ks * 32 + lg * 8;
    bf16x8 a[4], b[8];
#pragma unroll
    for (int f = 0; f < 8; ++f)
      b[f] = *(const bf16x8*)(Wb + (size_t)(f * 16 + lr) * K + koff);
#pragma unroll
    for (int mg = 0; mg < 4; ++mg)
      a[mg] = *(const bf16x8*)(NB + (size_t)(rbase + mg * 16 + lr) * K + koff);
#pragma unroll
    for (int mg = 0; mg < 4; ++mg)
#pragma unroll
      for (int f = 0; f < 8; ++f)
        acc[mg][f] = __builtin_amdgcn_mfma_f32_16x16x32_bf16(a[mg], b[f], acc[mg][f], 0, 0, 0);
  }

  float w2[8];
#pragma unroll
  for (int f = 0; f < 8; ++f) w2[f] = wa2[hb * 128 + f * 16 + lr];

#pragma unroll
  for (int mg = 0; mg < 4; ++mg) {
    const int i = blockIdx.x * 16 + w * 4 + mg;
    float tv[8];
#pragma unroll
    for (int f = 0; f < 8; ++f)
      tv[f] = Tb[(size_t)i * 512 + hb * 128 + f * 16 + lr];
    float sc[4];
#pragma unroll
    for (int r = 0; r < 4; ++r) {
      float s = 0.f;
#pragma unroll
      for (int f = 0; f < 8; ++f)
        s += fast_tanh(acc[mg][f][r] + tv[f]) * w2[f];
      s += __shfl_xor(s, 1); s += __shfl_xor(s, 2);
      s += __shfl_xor(s, 4); s += __shfl_xor(s, 8);
      sc[r] = s;
    }
    float mx = fmaxf(fmaxf(sc[0], sc[1]), fmaxf(sc[2], sc[3]));
    mx = fmaxf(mx, __shfl_xor(mx, 16));
    mx = fmaxf(mx, __shfl_xor(mx, 32));
    float e0 = fast_exp(sc[0] - mx), e1 = fast_exp(sc[1] - mx);
    float e2 = fast_exp(sc[2] - mx), e3 = fast_exp(sc[3] - mx);
    float sum = e0 + e1 + e2 + e3;
    sum += __shfl_xor(sum, 16); sum += __shfl_xor(sum, 32);
    float inv = 1.f / sum;
    if (lr == 0) {
      alsh[w][mg][lg * 4 + 0] = e0 * inv;
      alsh[w][mg][lg * 4 + 1] = e1 * inv;
      alsh[w][mg][lg * 4 + 2] = e2 * inv;
      alsh[w][mg][lg * 4 + 3] = e3 * inv;
    }
  }
  // No barrier: each wave reads only its own alsh[w] region (same-wave
  // LDS dependency; compiler orders via lgkmcnt).

  constexpr int NCH = K >> 7;   // 1 (K=128) or 2 (K=256)
#pragma unroll
  for (int mg = 0; mg < 4; ++mg) {
    const int i = blockIdx.x * 16 + w * 4 + mg;
    float al[16];
#pragma unroll
    for (int s = 0; s < 16; ++s) al[s] = alsh[w][mg][s];
#pragma unroll
    for (int c = 0; c < NCH; ++c) {
      const int d = l * 2 + c * 128;
      const unsigned short* nbp = NB + (size_t)(rbase + mg * 16) * K + d;
      float a0 = 0.f, a1 = 0.f;
#pragma unroll
      for (int s = 0; s < 16; ++s) {
        unsigned v = *(const unsigned*)(nbp + (size_t)s * K);
        a0 = fmaf(al[s], b2f((unsigned short)(v & 0xffffu)), a0);
        a1 = fmaf(al[s], b2f((unsigned short)(v >> 16)), a1);
      }
      unsigned o = (unsigned)f2b(a0) | ((unsigned)f2b(a1) << 16);
      *(unsigned*)(AG + ((size_t)i * 4 + hb) * K + d) = o;
    }
  }
}

// ---------------------------------------------------------------------------
// OUTG: out[m, hb*64+c] = relu( x @ Wx[hb] + agg[hb] @ Wn[hb] )  (MFMA)
// ---------------------------------------------------------------------------
template <int DX, bool OUTB>
__global__ __launch_bounds__(256) void outg_kernel(
    const unsigned short* __restrict__ Xb,   // [M][DX]
    const unsigned short* __restrict__ AG,   // [M][4][DX]
    const unsigned short* __restrict__ WXT,  // [4][64][DX]
    const unsigned short* __restrict__ WNT,  // [4][64][DX]
    void* __restrict__ outv) {               // [M][256]
  const int t = threadIdx.x;
  const int w = t >> 6, l = t & 63;
  const int lr = l & 15, lg = l >> 4;
  const int hb = blockIdx.y;
  const int rbase = blockIdx.x * 128 + w * 32;
  f32x4 acc[2][4] = {};
  constexpr int nks = DX >> 5;

#pragma unroll
  for (int ks = 0; ks < nks; ++ks) {
    const int koff = ks * 32 + lg * 8;
    bf16x8 a[2], b[4];
#pragma unroll
    for (int mg = 0; mg < 2; ++mg)
      a[mg] = *(const bf16x8*)(Xb + (size_t)(rbase + mg * 16 + lr) * DX + koff);
#pragma unroll
    for (int f = 0; f < 4; ++f)
      b[f] = *(const bf16x8*)(WXT + (size_t)(hb * 64 + f * 16 + lr) * DX + koff);
#pragma unroll
    for (int mg = 0; mg < 2; ++mg)
#pragma unroll
      for (int f = 0; f < 4; ++f)
        acc[mg][f] = __builtin_amdgcn_mfma_f32_16x16x32_bf16(a[mg], b[f], acc[mg][f], 0, 0, 0);
  }
#pragma unroll
  for (int ks = 0; ks < nks; ++ks) {
    const int koff = ks * 32 + lg * 8;
    bf16x8 a[2], b[4];
#pragma unroll
    for (int mg = 0; mg < 2; ++mg)
      a[mg] = *(const bf16x8*)(AG + ((size_t)(rbase + mg * 16 + lr) * 4 + hb) * DX + koff);
#pragma unroll
    for (int f = 0; f < 4; ++f)
      b[f] = *(const bf16x8*)(WNT + (size_t)(hb * 64 + f * 16 + lr) * DX + koff);
#pragma unroll
    for (int mg = 0; mg < 2; ++mg)
#pragma unroll
      for (int f = 0; f < 4; ++f)
        acc[mg][f] = __builtin_amdgcn_mfma_f32_16x16x32_bf16(a[mg], b[f], acc[mg][f], 0, 0, 0);
  }

#pragma unroll
  for (int mg = 0; mg < 2; ++mg)
#pragma unroll
    for (int f = 0; f < 4; ++f)
#pragma unroll
      for (int r = 0; r < 4; ++r) {
        float v = fmaxf(acc[mg][f][r], 0.f);
        size_t idx = (size_t)(rbase + mg * 16 + lg * 4 + r) * 256 + hb * 64 + f * 16 + lr;
        if (OUTB) ((unsigned short*)outv)[idx] = f2b(v);
        else      ((float*)outv)[idx] = v;
      }
}

// ---------------------------------------------------------------------------
extern "C" void kernel_launch(void* const* d_in, const int* in_sizes, int n_in,
                              void* d_out, int out_size, void* d_ws, size_t ws_size,
                              hipStream_t stream) {
  (void)in_sizes; (void)n_in; (void)out_size; (void)ws_size;
  const int*   ids   = (const int*)d_in[0];
  const float* feats = (const float*)d_in[1];
  const int*   adjs  = (const int*)d_in[2];
  const float* Wp    = (const float*)d_in[3];
  const float* Wa1_0 = (const float*)d_in[4];
  const float* wa2_0 = (const float*)d_in[5];
  const float* Wx_0  = (const float*)d_in[6];
  const float* Wn_0  = (const float*)d_in[7];
  const float* Wa1_1 = (const float*)d_in[8];
  const float* wa2_1 = (const float*)d_in[9];
  const float* Wx_1  = (const float*)d_in[10];
  const float* Wn_1  = (const float*)d_in[11];
  float* out = (float*)d_out;

  char* ws = (char*)d_ws;
  size_t off = 0;
  auto alloc = [&](size_t bytes) { char* p = ws + off; off += (bytes + 255) & ~(size_t)255; return p; };
  int*            nodes = (int*)alloc(139776 * 4);
  unsigned short* Pb    = (unsigned short*)alloc((size_t)139776 * 128 * 2);
  float*          T     = (float*)alloc((size_t)8192 * 512 * 4);
  unsigned short* AG    = (unsigned short*)alloc((size_t)8192 * 4 * 256 * 2);
  unsigned short* NF1b  = (unsigned short*)alloc((size_t)8192 * 256 * 2);
  unsigned short* NF0b  = (unsigned short*)alloc((size_t)512 * 256 * 2);
  unsigned short* WB    = (unsigned short*)alloc((size_t)1196032 * 2);

  unsigned short* Wpt  = WB;
  unsigned short* WT0  = WB + 16384;
  unsigned short* WT1  = WB + 278528;
  unsigned short* WXT0 = WB + 802816;
  unsigned short* WNT0 = WB + 868352;
  unsigned short* WXT1 = WB + 933888;
  unsigned short* WNT1 = WB + 1064960;

  transcast_kernel<<<4672, 256, 0, stream>>>(Wp, Wa1_0, Wa1_1, Wx_0, Wn_0,
                                             Wx_1, Wn_1, WB);

  for (int mp = 0; mp < 2; ++mp) {
    const int* adj = adjs + (size_t)mp * 200000 * 32;
    const float* w2_0 = wa2_0 + (size_t)mp * 4 * 128;
    const float* w2_1 = wa2_1 + (size_t)mp * 4 * 128;
    const unsigned short* WT0_top = WT0 + (size_t)mp * 2 * 65536;
    const unsigned short* WT0_bot = WT0 + ((size_t)mp * 2 + 1) * 65536;
    const unsigned short* WT1_top = WT1 + (size_t)mp * 2 * 131072;
    const unsigned short* WT1_bot = WT1 + ((size_t)mp * 2 + 1) * 131072;
    const unsigned short* wxt0 = WXT0 + (size_t)mp * 32768;
    const unsigned short* wnt0 = WNT0 + (size_t)mp * 32768;
    const unsigned short* wxt1 = WXT1 + (size_t)mp * 65536;
    const unsigned short* wnt1 = WNT1 + (size_t)mp * 65536;

    unsigned key0[2], key1[2];
    for (int li = 0; li < 2; ++li) {
      unsigned K0, K1;
      tf2x32(0u, 42u, 0u, (unsigned)(mp * 16 + li), K0, K1);
      tf2x32(K0, K1, 0u, 1u, key0[li], key1[li]);
    }

    frontier2_kernel<<<512, 256, 0, stream>>>(adj, ids, nodes,
                                              key0[0], key1[0], key0[1], key1[1]);

    mfma_gemm<0, true, 4><<<dim3(1092, 1), 256, 0, stream>>>(
        feats, nodes, Wpt, Pb, 128);

    const unsigned short* Pb0 = Pb;
    const unsigned short* Pb1 = Pb + (size_t)512 * 128;
    const unsigned short* Pb2 = Pb + (size_t)8704 * 128;

    // ---- L0 agg B: x=Pb1 (8192), nb=Pb2 (131072) -> NF1b
    mfma_gemm<1, false, 4><<<dim3(64, 4), 256, 0, stream>>>(
        Pb1, nullptr, WT0_top, T, 512);
    aggsc_mfma<4><<<dim3(512, 4), 256, 0, stream>>>(Pb2, T, WT0_bot, w2_0, AG);
    outg_kernel<128, true><<<dim3(64, 4), 256, 0, stream>>>(
        Pb1, AG, wxt0, wnt0, NF1b);

    // ---- L0 agg A: x=Pb0 (512), nb=Pb1 (8192) -> NF0b
    mfma_gemm<1, false, 4><<<dim3(4, 4), 256, 0, stream>>>(
        Pb0, nullptr, WT0_top, T, 512);
    aggsc_mfma<4><<<dim3(32, 4), 256, 0, stream>>>(Pb1, T, WT0_bot, w2_0, AG);
    outg_kernel<128, true><<<dim3(4, 4), 256, 0, stream>>>(
        Pb0, AG, wxt0, wnt0, NF0b);

    // ---- L1: x=NF0b (512), nb=NF1b (8192) -> d_out[mp] fp32
    mfma_gemm<1, false, 8><<<dim3(4, 4), 256, 0, stream>>>(
        NF0b, nullptr, WT1_top, T, 512);
    aggsc_mfma<8><<<dim3(32, 4), 256, 0, stream>>>(NF1b, T, WT1_bot, w2_1, AG);
    outg_kernel<256, false><<<dim3(4, 4), 256, 0, stream>>>(
        NF0b, AG, wxt1, wnt1, out + (size_t)mp * 512 * 256);
  }
}

// Round 9
// 362.011 us; speedup vs baseline: 3.7371x; 1.1236x over previous
//
#include <hip/hip_runtime.h>
#include <math.h>

// ---------------------------------------------------------------------------
// GraphSAGE-attention forward (round 9: aggsc = 64-row LDS-staged NB tile
// shared by 4 head-waves; NB read from HBM exactly once; AG phase from LDS).
// RNG verified R3. C/D layout (m89): col=lane&15, row=(lane>>4)*4+reg.
// ---------------------------------------------------------------------------

typedef __attribute__((ext_vector_type(8))) short bf16x8;
typedef __attribute__((ext_vector_type(4))) float f32x4;

__device__ __forceinline__ float b2f(unsigned short u) {
  union { unsigned u; float f; } c; c.u = ((unsigned)u) << 16; return c.f;
}
__device__ __forceinline__ unsigned short f2b(float f) {
  union { float f; unsigned u; } c; c.f = f;
  return (unsigned short)((c.u + 0x7FFFu + ((c.u >> 16) & 1u)) >> 16);
}

__device__ __forceinline__ float fast_tanh(float x) {
  float y = x * 2.8853900817779268f;   // 2*log2(e)
  float z; asm("v_exp_f32 %0, %1" : "=v"(z) : "v"(y));
  float zp1 = z + 1.f;
  float w; asm("v_rcp_f32 %0, %1" : "=v"(w) : "v"(zp1));
  return fmaf(-2.f, w, 1.f);
}
__device__ __forceinline__ float fast_exp(float x) {
  float y = x * 1.4426950408889634f;
  float z; asm("v_exp_f32 %0, %1" : "=v"(z) : "v"(y));
  return z;
}

__host__ __device__ __forceinline__ void tf2x32(unsigned k0, unsigned k1,
                                                unsigned x0, unsigned x1,
                                                unsigned& o0, unsigned& o1) {
  const unsigned ks2 = k0 ^ k1 ^ 0x1BD11BDAu;
  unsigned v0 = x0 + k0, v1 = x1 + k1;
#define TFR(r) { v0 += v1; v1 = (v1 << (r)) | (v1 >> (32 - (r))); v1 ^= v0; }
  TFR(13) TFR(15) TFR(26) TFR(6)
  v0 += k1;  v1 += ks2 + 1u;
  TFR(17) TFR(29) TFR(16) TFR(24)
  v0 += ks2; v1 += k0 + 2u;
  TFR(13) TFR(15) TFR(26) TFR(6)
  v0 += k0;  v1 += k1 + 3u;
  TFR(17) TFR(29) TFR(16) TFR(24)
  v0 += k1;  v1 += ks2 + 4u;
  TFR(13) TFR(15) TFR(26) TFR(6)
  v0 += ks2; v1 += k0 + 5u;
#undef TFR
  o0 = v0; o1 = v1;
}

__global__ void frontier2_kernel(const int* __restrict__ adj,
                                 const int* __restrict__ ids,
                                 int* __restrict__ nodes,
                                 unsigned k0a, unsigned k1a,
                                 unsigned k0b, unsigned k1b) {
  int i = blockIdx.x * 256 + threadIdx.x;
  int j = i >> 4;
  unsigned y0, y1;
  tf2x32(k0a, k1a, 0u, (unsigned)j, y0, y1);
  int col1 = (int)((y0 ^ y1) & 31u);
  int p0 = ids[j >> 4];
  int f1 = adj[(size_t)p0 * 32 + col1];
  tf2x32(k0b, k1b, 0u, (unsigned)i, y0, y1);
  int col2 = (int)((y0 ^ y1) & 31u);
  int f2 = adj[(size_t)f1 * 32 + col2];
  nodes[8704 + i] = f2;
  if ((i & 15) == 0) nodes[512 + j] = f1;
  if (i < 512) nodes[i] = ids[i];
}

// ---------------------------------------------------------------------------
// transcast: bf16 transposed weights, linear ranges (see R5 comment).
// ---------------------------------------------------------------------------
__global__ void transcast_kernel(const float* __restrict__ Wp,
                                 const float* __restrict__ Wa1_0,
                                 const float* __restrict__ Wa1_1,
                                 const float* __restrict__ Wx_0,
                                 const float* __restrict__ Wn_0,
                                 const float* __restrict__ Wx_1,
                                 const float* __restrict__ Wn_1,
                                 unsigned short* __restrict__ Wpt) {
  int o = blockIdx.x * 256 + threadIdx.x;
  if (o >= 1196032) return;
  float v;
  if (o < 16384) {
    int k = o & 127, c = o >> 7;
    v = Wp[k * 128 + c];
  } else if (o < 278528) {
    int o2 = o - 16384;
    int k = o2 & 127, c = (o2 >> 7) & 127, h = (o2 >> 14) & 3,
        half = (o2 >> 16) & 1, mpi = o2 >> 17;
    v = Wa1_0[(((size_t)(mpi * 4 + h) * 256) + half * 128 + k) * 128 + c];
  } else if (o < 802816) {
    int o3 = o - 278528;
    int k = o3 & 255, c = (o3 >> 8) & 127, h = (o3 >> 15) & 3,
        half = (o3 >> 17) & 1, mpi = o3 >> 18;
    v = Wa1_1[(((size_t)(mpi * 4 + h) * 512) + half * 256 + k) * 128 + c];
  } else if (o < 868352) {
    int o4 = o - 802816;
    int k = o4 & 127, oo = (o4 >> 7) & 63, h = (o4 >> 13) & 3, mpi = o4 >> 15;
    v = Wx_0[(((size_t)(mpi * 4 + h) * 128) + k) * 64 + oo];
  } else if (o < 933888) {
    int o4 = o - 868352;
    int k = o4 & 127, oo = (o4 >> 7) & 63, h = (o4 >> 13) & 3, mpi = o4 >> 15;
    v = Wn_0[(((size_t)(mpi * 4 + h) * 128) + k) * 64 + oo];
  } else if (o < 1064960) {
    int o5 = o - 933888;
    int k = o5 & 255, oo = (o5 >> 8) & 63, h = (o5 >> 14) & 3, mpi = o5 >> 16;
    v = Wx_1[(((size_t)(mpi * 4 + h) * 256) + k) * 64 + oo];
  } else {
    int o5 = o - 1064960;
    int k = o5 & 255, oo = (o5 >> 8) & 63, h = (o5 >> 14) & 3, mpi = o5 >> 16;
    v = Wn_1[(((size_t)(mpi * 4 + h) * 256) + k) * 64 + oo];
  }
  Wpt[o] = f2b(v);
}

// ---------------------------------------------------------------------------
// MFMA GEMM (prep / T): block = 128 rows x 128 cols, 4 waves x 32 rows.
// ---------------------------------------------------------------------------
template <int MODE, bool A_F32, int NKS>
__global__ __launch_bounds__(256) void mfma_gemm(
    const void* __restrict__ Av, const int* __restrict__ gather,
    const unsigned short* __restrict__ WT, void* __restrict__ Cv,
    int ldc) {
  constexpr int K = NKS * 32;
  const int t = threadIdx.x;
  const int w = t >> 6, l = t & 63;
  const int lr = l & 15, lg = l >> 4;
  const int hb = blockIdx.y;
  const int rbase = blockIdx.x * 128 + w * 32;

  const unsigned short* Wb = WT + (size_t)hb * 128 * K;
  f32x4 acc[2][8] = {};

  int arow[2];
#pragma unroll
  for (int mg = 0; mg < 2; ++mg) {
    int row = rbase + mg * 16 + lr;
    arow[mg] = gather ? gather[row] : row;
  }
  const float* Af = (const float*)Av;
  const unsigned short* Ab = (const unsigned short*)Av;

#pragma unroll
  for (int ks = 0; ks < NKS; ++ks) {
    const int koff = ks * 32 + lg * 8;
    bf16x8 a[2], b[8];
#pragma unroll
    for (int mg = 0; mg < 2; ++mg) {
      if (A_F32) {
        const float* p = Af + (size_t)arow[mg] * K + koff;
        float4 v0 = *(const float4*)p;
        float4 v1 = *(const float4*)(p + 4);
        union { short s[8]; bf16x8 v; } u;
        u.s[0] = (short)f2b(v0.x); u.s[1] = (short)f2b(v0.y);
        u.s[2] = (short)f2b(v0.z); u.s[3] = (short)f2b(v0.w);
        u.s[4] = (short)f2b(v1.x); u.s[5] = (short)f2b(v1.y);
        u.s[6] = (short)f2b(v1.z); u.s[7] = (short)f2b(v1.w);
        a[mg] = u.v;
      } else {
        a[mg] = *(const bf16x8*)(Ab + (size_t)arow[mg] * K + koff);
      }
    }
#pragma unroll
    for (int f = 0; f < 8; ++f)
      b[f] = *(const bf16x8*)(Wb + (size_t)(f * 16 + lr) * K + koff);
#pragma unroll
    for (int mg = 0; mg < 2; ++mg)
#pragma unroll
      for (int f = 0; f < 8; ++f)
        acc[mg][f] = __builtin_amdgcn_mfma_f32_16x16x32_bf16(a[mg], b[f], acc[mg][f], 0, 0, 0);
  }

  if (MODE == 0) {
    unsigned short* Cb = (unsigned short*)Cv;
#pragma unroll
    for (int mg = 0; mg < 2; ++mg)
#pragma unroll
      for (int f = 0; f < 8; ++f)
#pragma unroll
        for (int r = 0; r < 4; ++r)
          Cb[(size_t)(rbase + mg * 16 + lg * 4 + r) * ldc + f * 16 + lr] =
              f2b(acc[mg][f][r]);
  } else {
    float* Cf = (float*)Cv;
#pragma unroll
    for (int mg = 0; mg < 2; ++mg)
#pragma unroll
      for (int f = 0; f < 8; ++f)
#pragma unroll
        for (int r = 0; r < 4; ++r)
          Cf[(size_t)(rbase + mg * 16 + lg * 4 + r) * ldc + hb * 128 + f * 16 + lr] =
              acc[mg][f][r];
  }
}

// ---------------------------------------------------------------------------
// AGGSC+AGG fused (R9): grid = M/64; block = 4 waves = 4 heads sharing an
// LDS-staged 64-row NB tile (row pad +8 shorts -> uniform bank spread).
// Each wave: U = nb@Wa1_bot[head] over 64 rows (4 m-rows), score/softmax,
// AG[i][head][:] from LDS. NB global traffic = exactly once.
// ---------------------------------------------------------------------------
template <int NKS>
__global__ __launch_bounds__(256, 2) void aggsc_mfma(
    const unsigned short* __restrict__ NB,   // [M][K] bf16
    const float* __restrict__ Tb,            // [m][512]
    const unsigned short* __restrict__ WTbot,// [4][128][K] bf16
    const float* __restrict__ wa2,           // [4][128]
    unsigned short* __restrict__ AG) {       // [m][4][K] bf16
  constexpr int K = NKS * 32;
  constexpr int KP = K + 8;                  // padded row (shorts)
  const int t = threadIdx.x;
  const int w = t >> 6, l = t & 63;          // w = head
  const int lr = l & 15, lg = l >> 4;
  const int rbase = blockIdx.x * 64;

  __shared__ unsigned short NBs[64 * KP];
  __shared__ float alsh[4][4][16];           // [wave][mg][sample]

  // stage NB tile (64 x K) -> LDS, 16B per thread per iter
#pragma unroll
  for (int q = 0; q < NKS; ++q) {
    int c = q * 256 + t;                     // chunk of 8 shorts
    int row = c / (K / 8), kc = c % (K / 8);
    bf16x8 v = *(const bf16x8*)(NB + (size_t)(rbase + row) * K + kc * 8);
    *(bf16x8*)(&NBs[row * KP + kc * 8]) = v;
  }
  __syncthreads();

  const unsigned short* Wb = WTbot + (size_t)w * 128 * K;
  f32x4 acc[4][8] = {};

#pragma unroll
  for (int ks = 0; ks < NKS; ++ks) {
    const int koff = ks * 32 + lg * 8;
    bf16x8 a[4], b[8];
#pragma unroll
    for (int f = 0; f < 8; ++f)
      b[f] = *(const bf16x8*)(Wb + (size_t)(f * 16 + lr) * K + koff);
#pragma unroll
    for (int mg = 0; mg < 4; ++mg)
      a[mg] = *(const bf16x8*)(&NBs[(mg * 16 + lr) * KP + koff]);
#pragma unroll
    for (int mg = 0; mg < 4; ++mg)
#pragma unroll
      for (int f = 0; f < 8; ++f)
        acc[mg][f] = __builtin_amdgcn_mfma_f32_16x16x32_bf16(a[mg], b[f], acc[mg][f], 0, 0, 0);
  }

  float w2[8];
#pragma unroll
  for (int f = 0; f < 8; ++f) w2[f] = wa2[w * 128 + f * 16 + lr];

#pragma unroll
  for (int mg = 0; mg < 4; ++mg) {
    const int i = blockIdx.x * 4 + mg;
    float tv[8];
#pragma unroll
    for (int f = 0; f < 8; ++f)
      tv[f] = Tb[(size_t)i * 512 + w * 128 + f * 16 + lr];
    float sc[4];
#pragma unroll
    for (int r = 0; r < 4; ++r) {
      float s = 0.f;
#pragma unroll
      for (int f = 0; f < 8; ++f)
        s += fast_tanh(acc[mg][f][r] + tv[f]) * w2[f];
      s += __shfl_xor(s, 1); s += __shfl_xor(s, 2);
      s += __shfl_xor(s, 4); s += __shfl_xor(s, 8);
      sc[r] = s;
    }
    float mx = fmaxf(fmaxf(sc[0], sc[1]), fmaxf(sc[2], sc[3]));
    mx = fmaxf(mx, __shfl_xor(mx, 16));
    mx = fmaxf(mx, __shfl_xor(mx, 32));
    float e0 = fast_exp(sc[0] - mx), e1 = fast_exp(sc[1] - mx);
    float e2 = fast_exp(sc[2] - mx), e3 = fast_exp(sc[3] - mx);
    float sum = e0 + e1 + e2 + e3;
    sum += __shfl_xor(sum, 16); sum += __shfl_xor(sum, 32);
    float inv = 1.f / sum;
    if (lr == 0) {
      alsh[w][mg][lg * 4 + 0] = e0 * inv;
      alsh[w][mg][lg * 4 + 1] = e1 * inv;
      alsh[w][mg][lg * 4 + 2] = e2 * inv;
      alsh[w][mg][lg * 4 + 3] = e3 * inv;
    }
  }
  // no barrier: wave w reads only alsh[w] (same-wave LDS dep) and NBs is
  // read-only after the single staging barrier.

  constexpr int NCH = K >> 7;   // 1 (K=128) or 2 (K=256)
#pragma unroll
  for (int mg = 0; mg < 4; ++mg) {
    const int i = blockIdx.x * 4 + mg;
    float al[16];
#pragma unroll
    for (int s = 0; s < 16; ++s) al[s] = alsh[w][mg][s];
#pragma unroll
    for (int c = 0; c < NCH; ++c) {
      const int d = l * 2 + c * 128;
      float a0 = 0.f, a1 = 0.f;
#pragma unroll
      for (int s = 0; s < 16; ++s) {
        unsigned v = *(const unsigned*)(&NBs[(mg * 16 + s) * KP + d]);
        a0 = fmaf(al[s], b2f((unsigned short)(v & 0xffffu)), a0);
        a1 = fmaf(al[s], b2f((unsigned short)(v >> 16)), a1);
      }
      unsigned o = (unsigned)f2b(a0) | ((unsigned)f2b(a1) << 16);
      *(unsigned*)(AG + ((size_t)i * 4 + w) * K + d) = o;
    }
  }
}

// ---------------------------------------------------------------------------
// OUTG: out[m, hb*64+c] = relu( x @ Wx[hb] + agg[hb] @ Wn[hb] )  (MFMA)
// ---------------------------------------------------------------------------
template <int DX, bool OUTB>
__global__ __launch_bounds__(256) void outg_kernel(
    const unsigned short* __restrict__ Xb,   // [M][DX]
    const unsigned short* __restrict__ AG,   // [M][4][DX]
    const unsigned short* __restrict__ WXT,  // [4][64][DX]
    const unsigned short* __restrict__ WNT,  // [4][64][DX]
    void* __restrict__ outv) {               // [M][256]
  const int t = threadIdx.x;
  const int w = t >> 6, l = t & 63;
  const int lr = l & 15, lg = l >> 4;
  const int hb = blockIdx.y;
  const int rbase = blockIdx.x * 128 + w * 32;
  f32x4 acc[2][4] = {};
  constexpr int nks = DX >> 5;

#pragma unroll
  for (int ks = 0; ks < nks; ++ks) {
    const int koff = ks * 32 + lg * 8;
    bf16x8 a[2], b[4];
#pragma unroll
    for (int mg = 0; mg < 2; ++mg)
      a[mg] = *(const bf16x8*)(Xb + (size_t)(rbase + mg * 16 + lr) * DX + koff);
#pragma unroll
    for (int f = 0; f < 4; ++f)
      b[f] = *(const bf16x8*)(WXT + (size_t)(hb * 64 + f * 16 + lr) * DX + koff);
#pragma unroll
    for (int mg = 0; mg < 2; ++mg)
#pragma unroll
      for (int f = 0; f < 4; ++f)
        acc[mg][f] = __builtin_amdgcn_mfma_f32_16x16x32_bf16(a[mg], b[f], acc[mg][f], 0, 0, 0);
  }
#pragma unroll
  for (int ks = 0; ks < nks; ++ks) {
    const int koff = ks * 32 + lg * 8;
    bf16x8 a[2], b[4];
#pragma unroll
    for (int mg = 0; mg < 2; ++mg)
      a[mg] = *(const bf16x8*)(AG + ((size_t)(rbase + mg * 16 + lr) * 4 + hb) * DX + koff);
#pragma unroll
    for (int f = 0; f < 4; ++f)
      b[f] = *(const bf16x8*)(WNT + (size_t)(hb * 64 + f * 16 + lr) * DX + koff);
#pragma unroll
    for (int mg = 0; mg < 2; ++mg)
#pragma unroll
      for (int f = 0; f < 4; ++f)
        acc[mg][f] = __builtin_amdgcn_mfma_f32_16x16x32_bf16(a[mg], b[f], acc[mg][f], 0, 0, 0);
  }

#pragma unroll
  for (int mg = 0; mg < 2; ++mg)
#pragma unroll
    for (int f = 0; f < 4; ++f)
#pragma unroll
      for (int r = 0; r < 4; ++r) {
        float v = fmaxf(acc[mg][f][r], 0.f);
        size_t idx = (size_t)(rbase + mg * 16 + lg * 4 + r) * 256 + hb * 64 + f * 16 + lr;
        if (OUTB) ((unsigned short*)outv)[idx] = f2b(v);
        else      ((float*)outv)[idx] = v;
      }
}

// ---------------------------------------------------------------------------
extern "C" void kernel_launch(void* const* d_in, const int* in_sizes, int n_in,
                              void* d_out, int out_size, void* d_ws, size_t ws_size,
                              hipStream_t stream) {
  (void)in_sizes; (void)n_in; (void)out_size; (void)ws_size;
  const int*   ids   = (const int*)d_in[0];
  const float* feats = (const float*)d_in[1];
  const int*   adjs  = (const int*)d_in[2];
  const float* Wp    = (const float*)d_in[3];
  const float* Wa1_0 = (const float*)d_in[4];
  const float* wa2_0 = (const float*)d_in[5];
  const float* Wx_0  = (const float*)d_in[6];
  const float* Wn_0  = (const float*)d_in[7];
  const float* Wa1_1 = (const float*)d_in[8];
  const float* wa2_1 = (const float*)d_in[9];
  const float* Wx_1  = (const float*)d_in[10];
  const float* Wn_1  = (const float*)d_in[11];
  float* out = (float*)d_out;

  char* ws = (char*)d_ws;
  size_t off = 0;
  auto alloc = [&](size_t bytes) { char* p = ws + off; off += (bytes + 255) & ~(size_t)255; return p; };
  int*            nodes = (int*)alloc(139776 * 4);
  unsigned short* Pb    = (unsigned short*)alloc((size_t)139776 * 128 * 2);
  float*          T     = (float*)alloc((size_t)8192 * 512 * 4);
  unsigned short* AG    = (unsigned short*)alloc((size_t)8192 * 4 * 256 * 2);
  unsigned short* NF1b  = (unsigned short*)alloc((size_t)8192 * 256 * 2);
  unsigned short* NF0b  = (unsigned short*)alloc((size_t)512 * 256 * 2);
  unsigned short* WB    = (unsigned short*)alloc((size_t)1196032 * 2);

  unsigned short* Wpt  = WB;
  unsigned short* WT0  = WB + 16384;
  unsigned short* WT1  = WB + 278528;
  unsigned short* WXT0 = WB + 802816;
  unsigned short* WNT0 = WB + 868352;
  unsigned short* WXT1 = WB + 933888;
  unsigned short* WNT1 = WB + 1064960;

  transcast_kernel<<<4672, 256, 0, stream>>>(Wp, Wa1_0, Wa1_1, Wx_0, Wn_0,
                                             Wx_1, Wn_1, WB);

  for (int mp = 0; mp < 2; ++mp) {
    const int* adj = adjs + (size_t)mp * 200000 * 32;
    const float* w2_0 = wa2_0 + (size_t)mp * 4 * 128;
    const float* w2_1 = wa2_1 + (size_t)mp * 4 * 128;
    const unsigned short* WT0_top = WT0 + (size_t)mp * 2 * 65536;
    const unsigned short* WT0_bot = WT0 + ((size_t)mp * 2 + 1) * 65536;
    const unsigned short* WT1_top = WT1 + (size_t)mp * 2 * 131072;
    const unsigned short* WT1_bot = WT1 + ((size_t)mp * 2 + 1) * 131072;
    const unsigned short* wxt0 = WXT0 + (size_t)mp * 32768;
    const unsigned short* wnt0 = WNT0 + (size_t)mp * 32768;
    const unsigned short* wxt1 = WXT1 + (size_t)mp * 65536;
    const unsigned short* wnt1 = WNT1 + (size_t)mp * 65536;

    unsigned key0[2], key1[2];
    for (int li = 0; li < 2; ++li) {
      unsigned K0, K1;
      tf2x32(0u, 42u, 0u, (unsigned)(mp * 16 + li), K0, K1);
      tf2x32(K0, K1, 0u, 1u, key0[li], key1[li]);
    }

    frontier2_kernel<<<512, 256, 0, stream>>>(adj, ids, nodes,
                                              key0[0], key1[0], key0[1], key1[1]);

    mfma_gemm<0, true, 4><<<dim3(1092, 1), 256, 0, stream>>>(
        feats, nodes, Wpt, Pb, 128);

    const unsigned short* Pb0 = Pb;
    const unsigned short* Pb1 = Pb + (size_t)512 * 128;
    const unsigned short* Pb2 = Pb + (size_t)8704 * 128;

    // ---- L0 agg B: x=Pb1 (8192), nb=Pb2 (131072) -> NF1b
    mfma_gemm<1, false, 4><<<dim3(64, 4), 256, 0, stream>>>(
        Pb1, nullptr, WT0_top, T, 512);
    aggsc_mfma<4><<<2048, 256, 0, stream>>>(Pb2, T, WT0_bot, w2_0, AG);
    outg_kernel<128, true><<<dim3(64, 4), 256, 0, stream>>>(
        Pb1, AG, wxt0, wnt0, NF1b);

    // ---- L0 agg A: x=Pb0 (512), nb=Pb1 (8192) -> NF0b
    mfma_gemm<1, false, 4><<<dim3(4, 4), 256, 0, stream>>>(
        Pb0, nullptr, WT0_top, T, 512);
    aggsc_mfma<4><<<128, 256, 0, stream>>>(Pb1, T, WT0_bot, w2_0, AG);
    outg_kernel<128, true><<<dim3(4, 4), 256, 0, stream>>>(
        Pb0, AG, wxt0, wnt0, NF0b);

    // ---- L1: x=NF0b (512), nb=NF1b (8192) -> d_out[mp] fp32
    mfma_gemm<1, false, 8><<<dim3(4, 4), 256, 0, stream>>>(
        NF0b, nullptr, WT1_top, T, 512);
    aggsc_mfma<8><<<128, 256, 0, stream>>>(NF1b, T, WT1_bot, w2_1, AG);
    outg_kernel<256, false><<<dim3(4, 4), 256, 0, stream>>>(
        NF0b, AG, wxt1, wnt1, out + (size_t)mp * 512 * 256);
  }
}

// Round 10
// 297.923 us; speedup vs baseline: 4.5410x; 1.2151x over previous
//
#include <hip/hip_runtime.h>
#include <math.h>

// ---------------------------------------------------------------------------
// GraphSAGE-attention forward (round 10):
//  - prep ONCE for all 200k nodes (linear GEMM, bf16 P_all); consumers gather
//  - mp0/mp1 pipelines batched into single launches (blockIdx.z = mp)
// RNG verified R3. C/D layout (m89): col=lane&15, row=(lane>>4)*4+reg.
// ---------------------------------------------------------------------------

typedef __attribute__((ext_vector_type(8))) short bf16x8;
typedef __attribute__((ext_vector_type(4))) float f32x4;

__device__ __forceinline__ float b2f(unsigned short u) {
  union { unsigned u; float f; } c; c.u = ((unsigned)u) << 16; return c.f;
}
__device__ __forceinline__ unsigned short f2b(float f) {
  union { float f; unsigned u; } c; c.f = f;
  return (unsigned short)((c.u + 0x7FFFu + ((c.u >> 16) & 1u)) >> 16);
}

__device__ __forceinline__ float fast_tanh(float x) {
  float y = x * 2.8853900817779268f;   // 2*log2(e)
  float z; asm("v_exp_f32 %0, %1" : "=v"(z) : "v"(y));
  float zp1 = z + 1.f;
  float w; asm("v_rcp_f32 %0, %1" : "=v"(w) : "v"(zp1));
  return fmaf(-2.f, w, 1.f);
}
__device__ __forceinline__ float fast_exp(float x) {
  float y = x * 1.4426950408889634f;
  float z; asm("v_exp_f32 %0, %1" : "=v"(z) : "v"(y));
  return z;
}

__host__ __device__ __forceinline__ void tf2x32(unsigned k0, unsigned k1,
                                                unsigned x0, unsigned x1,
                                                unsigned& o0, unsigned& o1) {
  const unsigned ks2 = k0 ^ k1 ^ 0x1BD11BDAu;
  unsigned v0 = x0 + k0, v1 = x1 + k1;
#define TFR(r) { v0 += v1; v1 = (v1 << (r)) | (v1 >> (32 - (r))); v1 ^= v0; }
  TFR(13) TFR(15) TFR(26) TFR(6)
  v0 += k1;  v1 += ks2 + 1u;
  TFR(17) TFR(29) TFR(16) TFR(24)
  v0 += ks2; v1 += k0 + 2u;
  TFR(13) TFR(15) TFR(26) TFR(6)
  v0 += k0;  v1 += k1 + 3u;
  TFR(17) TFR(29) TFR(16) TFR(24)
  v0 += k1;  v1 += ks2 + 4u;
  TFR(13) TFR(15) TFR(26) TFR(6)
  v0 += ks2; v1 += k0 + 5u;
#undef TFR
  o0 = v0; o1 = v1;
}

// batched 2-hop frontier: blockIdx.z = mp
__global__ void frontier2_kernel(const int* __restrict__ adjs,
                                 const int* __restrict__ ids,
                                 int* __restrict__ nodes_all,
                                 unsigned a00, unsigned a01, unsigned b00, unsigned b01,
                                 unsigned a10, unsigned a11, unsigned b10, unsigned b11) {
  const int mp = blockIdx.z;
  const int* adj = adjs + (size_t)mp * 6400000;
  int* nodes = nodes_all + (size_t)mp * 139776;
  unsigned k0a = mp ? a10 : a00, k1a = mp ? a11 : a01;
  unsigned k0b = mp ? b10 : b00, k1b = mp ? b11 : b01;
  int i = blockIdx.x * 256 + threadIdx.x;
  int j = i >> 4;
  unsigned y0, y1;
  tf2x32(k0a, k1a, 0u, (unsigned)j, y0, y1);
  int col1 = (int)((y0 ^ y1) & 31u);
  int p0 = ids[j >> 4];
  int f1 = adj[(size_t)p0 * 32 + col1];
  tf2x32(k0b, k1b, 0u, (unsigned)i, y0, y1);
  int col2 = (int)((y0 ^ y1) & 31u);
  int f2 = adj[(size_t)f1 * 32 + col2];
  nodes[8704 + i] = f2;
  if ((i & 15) == 0) nodes[512 + j] = f1;
  if (i < 512) nodes[i] = ids[i];
}

// ---------------------------------------------------------------------------
// transcast (unchanged linear ranges, see R5)
// ---------------------------------------------------------------------------
__global__ void transcast_kernel(const float* __restrict__ Wp,
                                 const float* __restrict__ Wa1_0,
                                 const float* __restrict__ Wa1_1,
                                 const float* __restrict__ Wx_0,
                                 const float* __restrict__ Wn_0,
                                 const float* __restrict__ Wx_1,
                                 const float* __restrict__ Wn_1,
                                 unsigned short* __restrict__ Wpt) {
  int o = blockIdx.x * 256 + threadIdx.x;
  if (o >= 1196032) return;
  float v;
  if (o < 16384) {
    int k = o & 127, c = o >> 7;
    v = Wp[k * 128 + c];
  } else if (o < 278528) {
    int o2 = o - 16384;
    int k = o2 & 127, c = (o2 >> 7) & 127, h = (o2 >> 14) & 3,
        half = (o2 >> 16) & 1, mpi = o2 >> 17;
    v = Wa1_0[(((size_t)(mpi * 4 + h) * 256) + half * 128 + k) * 128 + c];
  } else if (o < 802816) {
    int o3 = o - 278528;
    int k = o3 & 255, c = (o3 >> 8) & 127, h = (o3 >> 15) & 3,
        half = (o3 >> 17) & 1, mpi = o3 >> 18;
    v = Wa1_1[(((size_t)(mpi * 4 + h) * 512) + half * 256 + k) * 128 + c];
  } else if (o < 868352) {
    int o4 = o - 802816;
    int k = o4 & 127, oo = (o4 >> 7) & 63, h = (o4 >> 13) & 3, mpi = o4 >> 15;
    v = Wx_0[(((size_t)(mpi * 4 + h) * 128) + k) * 64 + oo];
  } else if (o < 933888) {
    int o4 = o - 868352;
    int k = o4 & 127, oo = (o4 >> 7) & 63, h = (o4 >> 13) & 3, mpi = o4 >> 15;
    v = Wn_0[(((size_t)(mpi * 4 + h) * 128) + k) * 64 + oo];
  } else if (o < 1064960) {
    int o5 = o - 933888;
    int k = o5 & 255, oo = (o5 >> 8) & 63, h = (o5 >> 14) & 3, mpi = o5 >> 16;
    v = Wx_1[(((size_t)(mpi * 4 + h) * 256) + k) * 64 + oo];
  } else {
    int o5 = o - 1064960;
    int k = o5 & 255, oo = (o5 >> 8) & 63, h = (o5 >> 14) & 3, mpi = o5 >> 16;
    v = Wn_1[(((size_t)(mpi * 4 + h) * 256) + k) * 64 + oo];
  }
  Wpt[o] = f2b(v);
}

// ---------------------------------------------------------------------------
// MFMA GEMM: block = 128 rows x 128 cols, 4 waves. blockIdx.z = mp (strides).
// MODE 0: bf16 C (prep: A fp32, clamped rows)  MODE 1: f32 C at col hb*128.
// ---------------------------------------------------------------------------
template <int MODE, bool A_F32, int NKS>
__global__ __launch_bounds__(256) void mfma_gemm(
    const void* __restrict__ Av, const int* __restrict__ gather,
    const unsigned short* __restrict__ WT, void* __restrict__ Cv,
    int ldc, int mclamp, int a_str, int g_str, int w_str, int c_str) {
  constexpr int K = NKS * 32;
  const int t = threadIdx.x;
  const int w = t >> 6, l = t & 63;
  const int lr = l & 15, lg = l >> 4;
  const int hb = blockIdx.y;
  const int mp = blockIdx.z;
  const int rbase = blockIdx.x * 128 + w * 32;

  const unsigned short* Wb = WT + (size_t)mp * w_str + (size_t)hb * 128 * K;
  f32x4 acc[2][8] = {};

  int arow[2];
#pragma unroll
  for (int mg = 0; mg < 2; ++mg) {
    int row = rbase + mg * 16 + lr;
    arow[mg] = gather ? gather[(size_t)mp * g_str + row] : min(row, mclamp);
  }
  const float* Af = (const float*)Av;
  const unsigned short* Ab = ((const unsigned short*)Av) + (size_t)mp * a_str;

#pragma unroll
  for (int ks = 0; ks < NKS; ++ks) {
    const int koff = ks * 32 + lg * 8;
    bf16x8 a[2], b[8];
#pragma unroll
    for (int mg = 0; mg < 2; ++mg) {
      if (A_F32) {
        const float* p = Af + (size_t)arow[mg] * K + koff;
        float4 v0 = *(const float4*)p;
        float4 v1 = *(const float4*)(p + 4);
        union { short s[8]; bf16x8 v; } u;
        u.s[0] = (short)f2b(v0.x); u.s[1] = (short)f2b(v0.y);
        u.s[2] = (short)f2b(v0.z); u.s[3] = (short)f2b(v0.w);
        u.s[4] = (short)f2b(v1.x); u.s[5] = (short)f2b(v1.y);
        u.s[6] = (short)f2b(v1.z); u.s[7] = (short)f2b(v1.w);
        a[mg] = u.v;
      } else {
        a[mg] = *(const bf16x8*)(Ab + (size_t)arow[mg] * K + koff);
      }
    }
#pragma unroll
    for (int f = 0; f < 8; ++f)
      b[f] = *(const bf16x8*)(Wb + (size_t)(f * 16 + lr) * K + koff);
#pragma unroll
    for (int mg = 0; mg < 2; ++mg)
#pragma unroll
      for (int f = 0; f < 8; ++f)
        acc[mg][f] = __builtin_amdgcn_mfma_f32_16x16x32_bf16(a[mg], b[f], acc[mg][f], 0, 0, 0);
  }

  if (MODE == 0) {
    unsigned short* Cb = ((unsigned short*)Cv) + (size_t)mp * c_str;
#pragma unroll
    for (int mg = 0; mg < 2; ++mg)
#pragma unroll
      for (int f = 0; f < 8; ++f)
#pragma unroll
        for (int r = 0; r < 4; ++r)
          Cb[(size_t)(rbase + mg * 16 + lg * 4 + r) * ldc + f * 16 + lr] =
              f2b(acc[mg][f][r]);
  } else {
    float* Cf = ((float*)Cv) + (size_t)mp * c_str;
#pragma unroll
    for (int mg = 0; mg < 2; ++mg)
#pragma unroll
      for (int f = 0; f < 8; ++f)
#pragma unroll
        for (int r = 0; r < 4; ++r)
          Cf[(size_t)(rbase + mg * 16 + lg * 4 + r) * ldc + hb * 128 + f * 16 + lr] =
              acc[mg][f][r];
  }
}

// ---------------------------------------------------------------------------
// AGGSC+AGG fused: grid (M/64, 1, nmp); block = 4 waves = 4 heads sharing
// LDS-staged 64-row NB tile (rows optionally gathered from P_all).
// ---------------------------------------------------------------------------
template <int NKS>
__global__ __launch_bounds__(256, 2) void aggsc_mfma(
    const unsigned short* __restrict__ NB, const int* __restrict__ gather,
    const float* __restrict__ Tb, const unsigned short* __restrict__ WTbot,
    const float* __restrict__ wa2, unsigned short* __restrict__ AG,
    int nb_str, int g_str, int t_str, int w_str, int wa2_str, int ag_str) {
  constexpr int K = NKS * 32;
  constexpr int KP = K + 8;
  const int t = threadIdx.x;
  const int w = t >> 6, l = t & 63;          // w = head
  const int lr = l & 15, lg = l >> 4;
  const int mp = blockIdx.z;
  const int rbase = blockIdx.x * 64;

  __shared__ unsigned short NBs[64 * KP];
  __shared__ float alsh[4][4][16];

  const unsigned short* NBm = NB + (size_t)mp * nb_str;
  const int* gm = gather ? gather + (size_t)mp * g_str : nullptr;

#pragma unroll
  for (int q = 0; q < NKS; ++q) {
    int c = q * 256 + t;
    int row = c / (K / 8), kc = c % (K / 8);
    int src = gm ? gm[rbase + row] : (rbase + row);
    bf16x8 v = *(const bf16x8*)(NBm + (size_t)src * K + kc * 8);
    *(bf16x8*)(&NBs[row * KP + kc * 8]) = v;
  }
  __syncthreads();

  const unsigned short* Wb = WTbot + (size_t)mp * w_str + (size_t)w * 128 * K;
  f32x4 acc[4][8] = {};

#pragma unroll
  for (int ks = 0; ks < NKS; ++ks) {
    const int koff = ks * 32 + lg * 8;
    bf16x8 a[4], b[8];
#pragma unroll
    for (int f = 0; f < 8; ++f)
      b[f] = *(const bf16x8*)(Wb + (size_t)(f * 16 + lr) * K + koff);
#pragma unroll
    for (int mg = 0; mg < 4; ++mg)
      a[mg] = *(const bf16x8*)(&NBs[(mg * 16 + lr) * KP + koff]);
#pragma unroll
    for (int mg = 0; mg < 4; ++mg)
#pragma unroll
      for (int f = 0; f < 8; ++f)
        acc[mg][f] = __builtin_amdgcn_mfma_f32_16x16x32_bf16(a[mg], b[f], acc[mg][f], 0, 0, 0);
  }

  float w2[8];
#pragma unroll
  for (int f = 0; f < 8; ++f) w2[f] = wa2[(size_t)mp * wa2_str + w * 128 + f * 16 + lr];

#pragma unroll
  for (int mg = 0; mg < 4; ++mg) {
    const int i = blockIdx.x * 4 + mg;
    float tv[8];
#pragma unroll
    for (int f = 0; f < 8; ++f)
      tv[f] = Tb[(size_t)mp * t_str + (size_t)i * 512 + w * 128 + f * 16 + lr];
    float sc[4];
#pragma unroll
    for (int r = 0; r < 4; ++r) {
      float s = 0.f;
#pragma unroll
      for (int f = 0; f < 8; ++f)
        s += fast_tanh(acc[mg][f][r] + tv[f]) * w2[f];
      s += __shfl_xor(s, 1); s += __shfl_xor(s, 2);
      s += __shfl_xor(s, 4); s += __shfl_xor(s, 8);
      sc[r] = s;
    }
    float mx = fmaxf(fmaxf(sc[0], sc[1]), fmaxf(sc[2], sc[3]));
    mx = fmaxf(mx, __shfl_xor(mx, 16));
    mx = fmaxf(mx, __shfl_xor(mx, 32));
    float e0 = fast_exp(sc[0] - mx), e1 = fast_exp(sc[1] - mx);
    float e2 = fast_exp(sc[2] - mx), e3 = fast_exp(sc[3] - mx);
    float sum = e0 + e1 + e2 + e3;
    sum += __shfl_xor(sum, 16); sum += __shfl_xor(sum, 32);
    float inv = 1.f / sum;
    if (lr == 0) {
      alsh[w][mg][lg * 4 + 0] = e0 * inv;
      alsh[w][mg][lg * 4 + 1] = e1 * inv;
      alsh[w][mg][lg * 4 + 2] = e2 * inv;
      alsh[w][mg][lg * 4 + 3] = e3 * inv;
    }
  }
  // no barrier: wave reads only its own alsh[w]; NBs read-only after stage.

  constexpr int NCH = K >> 7;
#pragma unroll
  for (int mg = 0; mg < 4; ++mg) {
    const int i = blockIdx.x * 4 + mg;
    float al[16];
#pragma unroll
    for (int s = 0; s < 16; ++s) al[s] = alsh[w][mg][s];
#pragma unroll
    for (int c = 0; c < NCH; ++c) {
      const int d = l * 2 + c * 128;
      float a0 = 0.f, a1 = 0.f;
#pragma unroll
      for (int s = 0; s < 16; ++s) {
        unsigned v = *(const unsigned*)(&NBs[(mg * 16 + s) * KP + d]);
        a0 = fmaf(al[s], b2f((unsigned short)(v & 0xffffu)), a0);
        a1 = fmaf(al[s], b2f((unsigned short)(v >> 16)), a1);
      }
      unsigned o = (unsigned)f2b(a0) | ((unsigned)f2b(a1) << 16);
      *(unsigned*)(AG + (size_t)mp * ag_str + ((size_t)i * 4 + w) * K + d) = o;
    }
  }
}

// ---------------------------------------------------------------------------
// OUTG: out[m, hb*64+c] = relu(x@Wx[hb] + agg[hb]@Wn[hb]); X optionally
// gathered from P_all. blockIdx.z = mp.
// ---------------------------------------------------------------------------
template <int DX, bool OUTB>
__global__ __launch_bounds__(256) void outg_kernel(
    const unsigned short* __restrict__ Xb, const int* __restrict__ gatherX,
    const unsigned short* __restrict__ AG,
    const unsigned short* __restrict__ WXT, const unsigned short* __restrict__ WNT,
    void* __restrict__ outv,
    int x_str, int g_str, int ag_str, int w_str, int o_str) {
  const int t = threadIdx.x;
  const int w = t >> 6, l = t & 63;
  const int lr = l & 15, lg = l >> 4;
  const int hb = blockIdx.y;
  const int mp = blockIdx.z;
  const int rbase = blockIdx.x * 128 + w * 32;
  f32x4 acc[2][4] = {};
  constexpr int nks = DX >> 5;

  const unsigned short* Xm = Xb + (size_t)mp * x_str;
  const int* gm = gatherX ? gatherX + (size_t)mp * g_str : nullptr;
  const unsigned short* AGm = AG + (size_t)mp * ag_str;
  const unsigned short* WXm = WXT + (size_t)mp * w_str;
  const unsigned short* WNm = WNT + (size_t)mp * w_str;

  int xrow[2];
#pragma unroll
  for (int mg = 0; mg < 2; ++mg) {
    int row = rbase + mg * 16 + lr;
    xrow[mg] = gm ? gm[row] : row;
  }

#pragma unroll
  for (int ks = 0; ks < nks; ++ks) {
    const int koff = ks * 32 + lg * 8;
    bf16x8 a[2], b[4];
#pragma unroll
    for (int mg = 0; mg < 2; ++mg)
      a[mg] = *(const bf16x8*)(Xm + (size_t)xrow[mg] * DX + koff);
#pragma unroll
    for (int f = 0; f < 4; ++f)
      b[f] = *(const bf16x8*)(WXm + (size_t)(hb * 64 + f * 16 + lr) * DX + koff);
#pragma unroll
    for (int mg = 0; mg < 2; ++mg)
#pragma unroll
      for (int f = 0; f < 4; ++f)
        acc[mg][f] = __builtin_amdgcn_mfma_f32_16x16x32_bf16(a[mg], b[f], acc[mg][f], 0, 0, 0);
  }
#pragma unroll
  for (int ks = 0; ks < nks; ++ks) {
    const int koff = ks * 32 + lg * 8;
    bf16x8 a[2], b[4];
#pragma unroll
    for (int mg = 0; mg < 2; ++mg)
      a[mg] = *(const bf16x8*)(AGm + ((size_t)(rbase + mg * 16 + lr) * 4 + hb) * DX + koff);
#pragma unroll
    for (int f = 0; f < 4; ++f)
      b[f] = *(const bf16x8*)(WNm + (size_t)(hb * 64 + f * 16 + lr) * DX + koff);
#pragma unroll
    for (int mg = 0; mg < 2; ++mg)
#pragma unroll
      for (int f = 0; f < 4; ++f)
        acc[mg][f] = __builtin_amdgcn_mfma_f32_16x16x32_bf16(a[mg], b[f], acc[mg][f], 0, 0, 0);
  }

#pragma unroll
  for (int mg = 0; mg < 2; ++mg)
#pragma unroll
    for (int f = 0; f < 4; ++f)
#pragma unroll
      for (int r = 0; r < 4; ++r) {
        float v = fmaxf(acc[mg][f][r], 0.f);
        size_t idx = (size_t)mp * o_str +
                     (size_t)(rbase + mg * 16 + lg * 4 + r) * 256 + hb * 64 + f * 16 + lr;
        if (OUTB) ((unsigned short*)outv)[idx] = f2b(v);
        else      ((float*)outv)[idx] = v;
      }
}

// ---------------------------------------------------------------------------
extern "C" void kernel_launch(void* const* d_in, const int* in_sizes, int n_in,
                              void* d_out, int out_size, void* d_ws, size_t ws_size,
                              hipStream_t stream) {
  (void)in_sizes; (void)n_in; (void)out_size; (void)ws_size;
  const int*   ids   = (const int*)d_in[0];
  const float* feats = (const float*)d_in[1];
  const int*   adjs  = (const int*)d_in[2];
  const float* Wp    = (const float*)d_in[3];
  const float* Wa1_0 = (const float*)d_in[4];
  const float* wa2_0 = (const float*)d_in[5];
  const float* Wx_0  = (const float*)d_in[6];
  const float* Wn_0  = (const float*)d_in[7];
  const float* Wa1_1 = (const float*)d_in[8];
  const float* wa2_1 = (const float*)d_in[9];
  const float* Wx_1  = (const float*)d_in[10];
  const float* Wn_1  = (const float*)d_in[11];
  float* out = (float*)d_out;

  char* ws = (char*)d_ws;
  size_t off = 0;
  auto alloc = [&](size_t bytes) { char* p = ws + off; off += (bytes + 255) & ~(size_t)255; return p; };
  int*            nodes = (int*)alloc((size_t)2 * 139776 * 4);
  unsigned short* P_all = (unsigned short*)alloc((size_t)200064 * 128 * 2);
  float*          Tbig  = (float*)alloc((size_t)8192 * 512 * 4);
  float*          T2    = (float*)alloc((size_t)2 * 512 * 512 * 4);
  unsigned short* AGbig = (unsigned short*)alloc((size_t)8192 * 4 * 128 * 2);
  unsigned short* AG2   = (unsigned short*)alloc((size_t)2 * 512 * 4 * 256 * 2);
  unsigned short* NF1b  = (unsigned short*)alloc((size_t)2 * 8192 * 256 * 2);
  unsigned short* NF0b  = (unsigned short*)alloc((size_t)2 * 512 * 256 * 2);
  unsigned short* WB    = (unsigned short*)alloc((size_t)1196032 * 2);

  unsigned short* Wpt  = WB;
  unsigned short* WT0  = WB + 16384;     // [mp][half][h][128][128]
  unsigned short* WT1  = WB + 278528;    // [mp][half][h][128][256]
  unsigned short* WXT0 = WB + 802816;
  unsigned short* WNT0 = WB + 868352;
  unsigned short* WXT1 = WB + 933888;
  unsigned short* WNT1 = WB + 1064960;

  const int BIG = 1 << 30;

  // RNG keys for both mp
  unsigned key0[2][2], key1[2][2];
  for (int mp = 0; mp < 2; ++mp)
    for (int li = 0; li < 2; ++li) {
      unsigned K0, K1;
      tf2x32(0u, 42u, 0u, (unsigned)(mp * 16 + li), K0, K1);
      tf2x32(K0, K1, 0u, 1u, key0[mp][li], key1[mp][li]);
    }

  transcast_kernel<<<4672, 256, 0, stream>>>(Wp, Wa1_0, Wa1_1, Wx_0, Wn_0,
                                             Wx_1, Wn_1, WB);
  frontier2_kernel<<<dim3(512, 1, 2), 256, 0, stream>>>(
      adjs, ids, nodes,
      key0[0][0], key1[0][0], key0[0][1], key1[0][1],
      key0[1][0], key1[1][0], key0[1][1], key1[1][1]);

  // prep ALL nodes once: P_all = bf16(feats @ Wp)  [200064 rows, clamp reads]
  mfma_gemm<0, true, 4><<<dim3(1563, 1, 1), 256, 0, stream>>>(
      feats, nullptr, Wpt, P_all, 128, 199999, 0, 0, 0, 0);

  // ---- big stage (L0 agg B) per mp: x=frontier1, nb=frontier2 -> NF1b[mp]
  for (int mp = 0; mp < 2; ++mp) {
    int* nmp = nodes + (size_t)mp * 139776;
    mfma_gemm<1, false, 4><<<dim3(64, 4, 1), 256, 0, stream>>>(
        P_all, nmp + 512, WT0 + (size_t)mp * 2 * 65536, Tbig, 512, BIG, 0, 0, 0, 0);
    aggsc_mfma<4><<<dim3(2048, 1, 1), 256, 0, stream>>>(
        P_all, nmp + 8704, Tbig, WT0 + ((size_t)mp * 2 + 1) * 65536,
        wa2_0 + (size_t)mp * 512, AGbig, 0, 0, 0, 0, 0, 0);
    outg_kernel<128, true><<<dim3(64, 4, 1), 256, 0, stream>>>(
        P_all, nmp + 512, AGbig, WXT0 + (size_t)mp * 32768, WNT0 + (size_t)mp * 32768,
        NF1b + (size_t)mp * 2097152, 0, 0, 0, 0, 0);
  }

  // ---- L0 agg A (batched over mp): x=P_all[ids], nb=P_all[frontier1] -> NF0b
  mfma_gemm<1, false, 4><<<dim3(4, 4, 2), 256, 0, stream>>>(
      P_all, nodes, WT0, T2, 512, BIG, 0, 139776, 131072, 262144);
  aggsc_mfma<4><<<dim3(128, 1, 2), 256, 0, stream>>>(
      P_all, nodes + 512, T2, WT0 + 65536, wa2_0, AG2,
      0, 139776, 262144, 131072, 512, 262144);
  outg_kernel<128, true><<<dim3(4, 4, 2), 256, 0, stream>>>(
      P_all, nodes, AG2, WXT0, WNT0, NF0b, 0, 139776, 262144, 32768, 131072);

  // ---- L1 (batched over mp): x=NF0b, nb=NF1b -> d_out
  mfma_gemm<1, false, 8><<<dim3(4, 4, 2), 256, 0, stream>>>(
      NF0b, nullptr, WT1, T2, 512, 511, 131072, 0, 262144, 262144);
  aggsc_mfma<8><<<dim3(128, 1, 2), 256, 0, stream>>>(
      NF1b, nullptr, T2, WT1 + 131072, wa2_1, AG2,
      2097152, 0, 262144, 262144, 512, 524288);
  outg_kernel<256, false><<<dim3(4, 4, 2), 256, 0, stream>>>(
      NF0b, nullptr, AG2, WXT1, WNT1, out, 131072, 0, 524288, 65536, 131072);
}